// Round 1
// baseline (3494.989 us; speedup 1.0000x reference)
//
#include <hip/hip_runtime.h>
#include <stdint.h>
#include <math.h>

// Match XLA-CPU's unfused mul/add on threshold-critical math.
#pragma clang fp contract(off)

// RBMODE 0: partitionable threefry (JAX >= 0.4.30 default):
//   split: k_i = tf(key,(0,i)) (both output words); bits[e] = o0^o1 of tf(key,(0,e))
// RBMODE 1: original threefry: split via iota(4) halves; bits via half-split scheme.
#define RBMODE 0

#define NB   8
#define NPTS 2048
#define NS   1024
#define NG   30

// ---------------- threefry2x32 (Random123 / JAX, 20 rounds) ----------------
__host__ __device__ __forceinline__ uint32_t rotl32(uint32_t x, int r){
  return (x << r) | (x >> (32 - r));
}
__host__ __device__ __forceinline__ void tf2x32(uint32_t k0, uint32_t k1,
                                                uint32_t x0, uint32_t x1,
                                                uint32_t& o0, uint32_t& o1){
  uint32_t k2 = k0 ^ k1 ^ 0x1BD11BDAu;
  x0 += k0; x1 += k1;
#define TFR(r) { x0 += x1; x1 = rotl32(x1, (r)); x1 ^= x0; }
  TFR(13) TFR(15) TFR(26) TFR(6)
  x0 += k1; x1 += k2 + 1u;
  TFR(17) TFR(29) TFR(16) TFR(24)
  x0 += k2; x1 += k0 + 2u;
  TFR(13) TFR(15) TFR(26) TFR(6)
  x0 += k0; x1 += k1 + 3u;
  TFR(17) TFR(29) TFR(16) TFR(24)
  x0 += k1; x1 += k2 + 4u;
  TFR(13) TFR(15) TFR(26) TFR(6)
  x0 += k2; x1 += k0 + 5u;
#undef TFR
  o0 = x0; o1 = x1;
}

__device__ __forceinline__ uint32_t rand_bits(uint32_t k0, uint32_t k1, uint32_t e, uint32_t half){
#if RBMODE == 0
  (void)half;
  uint32_t o0, o1; tf2x32(k0, k1, 0u, e, o0, o1);
  return o0 ^ o1;
#else
  uint32_t o0, o1;
  if (e < half){ tf2x32(k0, k1, e, e + half, o0, o1); return o0; }
  else         { tf2x32(k0, k1, e - half, e, o0, o1); return o1; }
#endif
}

// jax.random.uniform(minval=1e-9, maxval=1.0) -> gumbel
__device__ __forceinline__ float gumbel_from(uint32_t bits){
  float f = __uint_as_float((bits >> 9) | 0x3f800000u) - 1.0f;  // [0,1)
  float u = fmaxf(1e-9f, f + 1e-9f);   // (maxval-minval)==1.0f exactly in f32
  return -logf(-logf(u));
}

// ---------------- sort keys: (value desc, index asc) ----------------
__device__ __forceinline__ unsigned long long packkey(float v, uint32_t idx){
  uint32_t u = __float_as_uint(v);
  u = (u & 0x80000000u) ? ~u : (u | 0x80000000u);  // monotone float->uint
  return ((unsigned long long)u << 32) | (unsigned long long)(0xFFFFFFFFu - idx);
}
__device__ __forceinline__ uint32_t unpackidx(unsigned long long k){
  return 0xFFFFFFFFu - (uint32_t)(k & 0xFFFFFFFFull);
}

__device__ __forceinline__ void bitonic_desc(unsigned long long* a, int M, int t, int T){
  for (int k = 2; k <= M; k <<= 1){
    for (int j = k >> 1; j > 0; j >>= 1){
      for (int i = t; i < M; i += T){
        int ixj = i ^ j;
        if (ixj > i){
          unsigned long long ai = a[i], aj = a[ixj];
          bool desc = ((i & k) == 0);
          if (desc ? (ai < aj) : (ai > aj)){ a[i] = aj; a[ixj] = ai; }
        }
      }
      __syncthreads();
    }
  }
}

// ---------------- kernel 0: nan/inf cleanup + softmax + log ----------------
__global__ __launch_bounds__(256) void ghv_softmax(const float* __restrict__ win,
                                                   float* __restrict__ w,
                                                   float* __restrict__ logw){
  int b = blockIdx.x, t = threadIdx.x;
  __shared__ float sh[NPTS];
  __shared__ float red[4];
  __shared__ float bcast;
  for (int n = t; n < NPTS; n += 256){
    float x = win[b*NPTS + n];
    if (isnan(x)) x = 1e-7f;
    if (isinf(x)) x = 1.0f;
    sh[n] = x;
  }
  __syncthreads();
  float m = -INFINITY;
  for (int n = t; n < NPTS; n += 256) m = fmaxf(m, sh[n]);
  for (int off = 32; off >= 1; off >>= 1) m = fmaxf(m, __shfl_down(m, off));
  if ((t & 63) == 0) red[t >> 6] = m;
  __syncthreads();
  if (t == 0) bcast = fmaxf(fmaxf(red[0], red[1]), fmaxf(red[2], red[3]));
  __syncthreads();
  float mx = bcast;
  float ss = 0.0f;
  for (int n = t; n < NPTS; n += 256){ float e = expf(sh[n] - mx); sh[n] = e; ss += e; }
  for (int off = 32; off >= 1; off >>= 1) ss += __shfl_down(ss, off);
  if ((t & 63) == 0) red[t >> 6] = ss;
  __syncthreads();
  if (t == 0) bcast = red[0] + red[1] + red[2] + red[3];
  __syncthreads();
  float tot = bcast;
  for (int n = t; n < NPTS; n += 256){
    float wv = sh[n] / tot;
    w[b*NPTS + n] = wv;
    logw[b*NPTS + n] = logf(wv);
  }
}

// ---------------- kernel 1: seed gumbel top-1024 + gather ----------------
// seeds layout: [b][s][8] = {sx,sy,sz,cx,cy,cz,w,pad}
__global__ __launch_bounds__(1024) void ghv_seed(const float* __restrict__ src,
                                                 const float* __restrict__ tgt,
                                                 const float* __restrict__ w,
                                                 const float* __restrict__ logw,
                                                 float* __restrict__ seeds,
                                                 uint32_t k0, uint32_t k1){
  __shared__ unsigned long long keys[NPTS];
  int b = blockIdx.x, t = threadIdx.x;
  for (int n = t; n < NPTS; n += 1024){
    uint32_t bits = rand_bits(k0, k1, (uint32_t)(b*NPTS + n), (uint32_t)(NB*NPTS/2));
    float v = logw[b*NPTS + n] + gumbel_from(bits);
    keys[n] = packkey(v, (uint32_t)n);
  }
  __syncthreads();
  bitonic_desc(keys, NPTS, t, 1024);
  int s = t;  // first NS entries, in top_k order
  uint32_t idx = unpackidx(keys[s]);
  const float* sb = src + b*3*NPTS;
  const float* tb = tgt + b*3*NPTS;
  float* sp = seeds + (size_t)((b << 10) + s) * 8;
  sp[0] = sb[idx]; sp[1] = sb[NPTS + idx]; sp[2] = sb[2*NPTS + idx];
  sp[3] = tb[idx]; sp[4] = tb[NPTS + idx]; sp[5] = tb[2*NPTS + idx];
  sp[6] = w[b*NPTS + idx]; sp[7] = 0.0f;
}

// ---------------- kernel 2: consensus + gumbel top-30 per (b,s) row ----------------
__global__ __launch_bounds__(512) void ghv_nn(const float* __restrict__ seeds,
                                              int* __restrict__ nn,
                                              uint32_t k0, uint32_t k1){
  __shared__ unsigned long long keys[NS];
  __shared__ float cons_sh[NS];
  __shared__ float red[8];
  __shared__ float srow[8];
  __shared__ float rowsum_sh;
  int s = blockIdx.x, b = blockIdx.y, t = threadIdx.x;
  if (t < 8) srow[t] = seeds[(size_t)((b << 10) + s)*8 + t];
  __syncthreads();
  float part = 0.0f;
  for (int q = 0; q < 2; ++q){
    int j = t + q*512;
    const float4* jp = (const float4*)(seeds + (size_t)((b << 10) + j)*8);
    float4 p0 = jp[0], p1 = jp[1];
    float dxs = srow[0]-p0.x, dys = srow[1]-p0.y, dzs = srow[2]-p0.z;
    float ds  = sqrtf(dxs*dxs + dys*dys + dzs*dzs);
    float dxc = srow[3]-p0.w, dyc = srow[4]-p1.x, dzc = srow[5]-p1.y;
    float dc  = sqrtf(dxc*dxc + dyc*dyc + dzc*dzc);
    float diff = ds - dc;
    float cons = expf((-(diff*diff)) / 0.01f);   // -(d**2)/SIGMA
    cons = fmaxf(cons, 0.1f);                    // clip(., 0.1, None)
    cons_sh[j] = cons;
    part += cons;
  }
  for (int off = 32; off >= 1; off >>= 1) part += __shfl_down(part, off);
  if ((t & 63) == 0) red[t >> 6] = part;
  __syncthreads();
  if (t == 0){ float tot = 0.0f; for (int i = 0; i < 8; ++i) tot += red[i]; rowsum_sh = tot; }
  __syncthreads();
  float rowsum = rowsum_sh;
  for (int q = 0; q < 2; ++q){
    int j = t + q*512;
    uint32_t e = (uint32_t)((b << 20) + (s << 10) + j);   // flat index in (B,S,S)
    uint32_t bits = rand_bits(k0, k1, e, (uint32_t)(NB*NS*NS/2));
    float v = logf(cons_sh[j] / rowsum) + gumbel_from(bits);
    keys[j] = packkey(v, (uint32_t)j);
  }
  __syncthreads();
  bitonic_desc(keys, NS, t, 512);
  if (t < 32){
    int v = (t < NG) ? (int)unpackidx(keys[t]) : 0;
    nn[(size_t)((b << 10) + s)*32 + t] = v;
  }
}

// ---------------- kernel 3: weighted Kabsch + 3x3 SVD (double) ----------------
__global__ __launch_bounds__(256) void ghv_kabsch(const float* __restrict__ seeds,
                                                  const int* __restrict__ nn,
                                                  float* __restrict__ Rt){
  int id = blockIdx.x*256 + threadIdx.x;
  if (id >= NB*NS) return;
  int b = id >> 10;
  const int* nnp = nn + (size_t)id*32;

  // pass 1: raw coordinate sums + weight sum (order g=0..29, like the ref)
  float sxs=0, sys=0, szs=0, cxs=0, cys=0, czs=0, wsum=0;
  for (int g = 0; g < NG; ++g){
    int j = nnp[g];
    const float4* jp = (const float4*)(seeds + (size_t)((b << 10) + j)*8);
    float4 p0 = jp[0], p1 = jp[1];
    sxs += p0.x; sys += p0.y; szs += p0.z;
    cxs += p0.w; cys += p1.x; czs += p1.y;
    wsum += p1.z;
  }
  float msx = sxs/30.0f, msy = sys/30.0f, msz = szs/30.0f;
  float mcx = cxs/30.0f, mcy = cys/30.0f, mcz = czs/30.0f;

  // pass 2: H = (src_c * w2) @ corr_c^T   (f32, like the ref)
  float Hf[9] = {0,0,0,0,0,0,0,0,0};
  for (int g = 0; g < NG; ++g){
    int j = nnp[g];
    const float4* jp = (const float4*)(seeds + (size_t)((b << 10) + j)*8);
    float4 p0 = jp[0], p1 = jp[1];
    float wg = p1.z / wsum;
    float a0 = p0.x - msx, a1 = p0.y - msy, a2 = p0.z - msz;
    float b0 = p0.w - mcx, b1 = p1.x - mcy, b2 = p1.y - mcz;
    float a0w = a0*wg, a1w = a1*wg, a2w = a2*wg;
    Hf[0] += a0w*b0; Hf[1] += a0w*b1; Hf[2] += a0w*b2;
    Hf[3] += a1w*b0; Hf[4] += a1w*b1; Hf[5] += a1w*b2;
    Hf[6] += a2w*b0; Hf[7] += a2w*b1; Hf[8] += a2w*b2;
  }

  // SVD in double: A = H^T H, cyclic Jacobi
  double H[9]; for (int i = 0; i < 9; ++i) H[i] = (double)Hf[i];
  double A[3][3];
  A[0][0] = H[0]*H[0] + H[3]*H[3] + H[6]*H[6];
  A[0][1] = H[0]*H[1] + H[3]*H[4] + H[6]*H[7];
  A[0][2] = H[0]*H[2] + H[3]*H[5] + H[6]*H[8];
  A[1][1] = H[1]*H[1] + H[4]*H[4] + H[7]*H[7];
  A[1][2] = H[1]*H[2] + H[4]*H[5] + H[7]*H[8];
  A[2][2] = H[2]*H[2] + H[5]*H[5] + H[8]*H[8];
  A[1][0] = A[0][1]; A[2][0] = A[0][2]; A[2][1] = A[1][2];
  double V[3][3] = {{1,0,0},{0,1,0},{0,0,1}};
  for (int sw = 0; sw < 12; ++sw){
    for (int p = 0; p < 2; ++p){
      for (int q = p+1; q < 3; ++q){
        double apq = A[p][q];
        if (fabs(apq) > 1e-300){
          double th = (A[q][q] - A[p][p]) / (2.0*apq);
          double tt = copysign(1.0, th) / (fabs(th) + sqrt(1.0 + th*th));
          double c  = 1.0 / sqrt(1.0 + tt*tt), sn = tt*c;
          int r = 3 - p - q;
          double app = A[p][p], aqq = A[q][q];
          double arp = A[r][p], arq = A[r][q];
          A[p][p] = app - tt*apq;
          A[q][q] = aqq + tt*apq;
          A[p][q] = 0.0; A[q][p] = 0.0;
          A[r][p] = c*arp - sn*arq; A[p][r] = A[r][p];
          A[r][q] = sn*arp + c*arq; A[q][r] = A[r][q];
          for (int kk = 0; kk < 3; ++kk){
            double vp = V[kk][p], vq = V[kk][q];
            V[kk][p] = c*vp - sn*vq;
            V[kk][q] = sn*vp + c*vq;
          }
        }
      }
    }
  }
  // sort eigenpairs descending
  int o0 = 0, o1 = 1, o2 = 2;
  double l0 = A[0][0], l1 = A[1][1], l2 = A[2][2];
  double tmp; int ti;
  if (l0 < l1){ tmp=l0; l0=l1; l1=tmp; ti=o0; o0=o1; o1=ti; }
  if (l0 < l2){ tmp=l0; l0=l2; l2=tmp; ti=o0; o0=o2; o2=ti; }
  if (l1 < l2){ tmp=l1; l1=l2; l2=tmp; ti=o1; o1=o2; o2=ti; }
  double v0[3] = {V[0][o0], V[1][o0], V[2][o0]};
  double v1[3] = {V[0][o1], V[1][o1], V[2][o1]};
  double v2[3] = {V[0][o2], V[1][o2], V[2][o2]};

  double u0[3], u1[3], u2[3];
  for (int i = 0; i < 3; ++i) u0[i] = H[i*3+0]*v0[0] + H[i*3+1]*v0[1] + H[i*3+2]*v0[2];
  double n0 = sqrt(u0[0]*u0[0] + u0[1]*u0[1] + u0[2]*u0[2]);
  if (n0 > 1e-150){ u0[0]/=n0; u0[1]/=n0; u0[2]/=n0; }
  else { u0[0]=1; u0[1]=0; u0[2]=0; }
  for (int i = 0; i < 3; ++i) u1[i] = H[i*3+0]*v1[0] + H[i*3+1]*v1[1] + H[i*3+2]*v1[2];
  double d01 = u0[0]*u1[0] + u0[1]*u1[1] + u0[2]*u1[2];
  for (int i = 0; i < 3; ++i) u1[i] -= d01*u0[i];
  double n1 = sqrt(u1[0]*u1[0] + u1[1]*u1[1] + u1[2]*u1[2]);
  if (n1 > 1e-150){ u1[0]/=n1; u1[1]/=n1; u1[2]/=n1; }
  else {
    double ax = fabs(u0[0]), ay = fabs(u0[1]), az = fabs(u0[2]);
    double e[3] = {0,0,0};
    if (ax <= ay && ax <= az) e[0] = 1; else if (ay <= az) e[1] = 1; else e[2] = 1;
    double de = u0[0]*e[0] + u0[1]*e[1] + u0[2]*e[2];
    for (int i = 0; i < 3; ++i) u1[i] = e[i] - de*u0[i];
    double nn1 = sqrt(u1[0]*u1[0] + u1[1]*u1[1] + u1[2]*u1[2]);
    for (int i = 0; i < 3; ++i) u1[i] /= nn1;
  }
  u2[0] = u0[1]*u1[2] - u0[2]*u1[1];
  u2[1] = u0[2]*u1[0] - u0[0]*u1[2];
  u2[2] = u0[0]*u1[1] - u0[1]*u1[0];
  // det(U)=+1 by construction -> detv = det(V_sorted)
  double detV = v0[0]*(v1[1]*v2[2] - v1[2]*v2[1])
              - v0[1]*(v1[0]*v2[2] - v1[2]*v2[0])
              + v0[2]*(v1[0]*v2[1] - v1[1]*v2[0]);
  // R[i][j] = v0[i]u0[j] + v1[i]u1[j] + detV * v2[i]u2[j]
  float Rf[9];
  for (int i = 0; i < 3; ++i)
    for (int j = 0; j < 3; ++j)
      Rf[i*3+j] = (float)(v0[i]*u0[j] + v1[i]*u1[j] + detV*(v2[i]*u2[j]));
  float tx = -(Rf[0]*msx + Rf[1]*msy + Rf[2]*msz) + mcx;
  float ty = -(Rf[3]*msx + Rf[4]*msy + Rf[5]*msz) + mcy;
  float tz = -(Rf[6]*msx + Rf[7]*msy + Rf[8]*msz) + mcz;
  float* o = Rt + (size_t)id*12;
  for (int i = 0; i < 9; ++i) o[i] = Rf[i];
  o[9] = tx; o[10] = ty; o[11] = tz;
}

// ---------------- kernel 4: fitness = #(||R src + t - tgt|| < 0.1) ----------------
__global__ __launch_bounds__(256) void ghv_fitness(const float* __restrict__ src,
                                                   const float* __restrict__ tgt,
                                                   const float* __restrict__ Rt,
                                                   int* __restrict__ fit){
  int id = blockIdx.x;
  int b = id >> 10;
  const float* rt = Rt + (size_t)id*12;
  float R0 = rt[0], R1 = rt[1], R2 = rt[2];
  float R3 = rt[3], R4 = rt[4], R5 = rt[5];
  float R6 = rt[6], R7 = rt[7], R8 = rt[8];
  float t0 = rt[9], t1 = rt[10], t2 = rt[11];
  const float* sb = src + b*3*NPTS;
  const float* tb = tgt + b*3*NPTS;
  int cnt = 0;
  for (int n = threadIdx.x; n < NPTS; n += 256){
    float x = sb[n], y = sb[n + NPTS], z = sb[n + 2*NPTS];
    float px = R0*x + R1*y + R2*z + t0;
    float py = R3*x + R4*y + R5*z + t1;
    float pz = R6*x + R7*y + R8*z + t2;
    float dx = px - tb[n], dy = py - tb[n + NPTS], dz = pz - tb[n + 2*NPTS];
    float l2 = sqrtf(dx*dx + dy*dy + dz*dz);
    cnt += (l2 < 0.1f) ? 1 : 0;
  }
  for (int off = 32; off >= 1; off >>= 1) cnt += __shfl_down(cnt, off);
  __shared__ int ws4[4];
  if ((threadIdx.x & 63) == 0) ws4[threadIdx.x >> 6] = cnt;
  __syncthreads();
  if (threadIdx.x == 0) fit[id] = ws4[0] + ws4[1] + ws4[2] + ws4[3];
}

// ---------------- kernel 5: argmax / vv / select-best-iteration ----------------
__global__ __launch_bounds__(512) void ghv_select(const float* __restrict__ Rt,
                                                  const int* __restrict__ fit,
                                                  float* __restrict__ dist_ws,
                                                  float* __restrict__ out,
                                                  int first){
  __shared__ int mc[8], mi[8];
  __shared__ int flag;
  int t = threadIdx.x;
  int b = t >> 6, lane = t & 63;
  int bc = -1, bi = 0;
  for (int s = lane; s < NS; s += 64){
    int c = fit[(b << 10) + s];
    if (c > bc){ bc = c; bi = s; }       // first occurrence of max (jnp.argmax)
  }
  for (int off = 32; off >= 1; off >>= 1){
    int oc = __shfl_down(bc, off);
    int oi = __shfl_down(bi, off);
    if (oc > bc || (oc == bc && oi < bi)){ bc = oc; bi = oi; }
  }
  if (lane == 0){ mc[b] = bc; mi[b] = bi; }
  __syncthreads();
  if (t == 0){
    int sum = 0; for (int i = 0; i < 8; ++i) sum += mc[i];
    float vv = (float)sum / 16384.0f;    // exact: mean_b(max_s count/2048)
    float dist = first ? 1e8f : dist_ws[0];
    int better = (vv < dist) ? 1 : 0;
    if (better) dist_ws[0] = vv;
    flag = better;
  }
  __syncthreads();
  if (flag){
    for (int i = t; i < 96; i += 512){
      float v;
      if (i < 72){
        int bb = i / 9, k = i % 9;
        v = Rt[(size_t)((bb << 10) + mi[bb])*12 + k];
      } else {
        int ii = i - 72; int bb = ii / 3, k = ii % 3;
        v = Rt[(size_t)((bb << 10) + mi[bb])*12 + 9 + k];
      }
      out[i] = v;
    }
  }
}

// ---------------- host ----------------
extern "C" void kernel_launch(void* const* d_in, const int* in_sizes, int n_in,
                              void* d_out, int out_size, void* d_ws, size_t ws_size,
                              hipStream_t stream){
  const float* src = (const float*)d_in[0];   // [8,3,2048]
  const float* tgt = (const float*)d_in[1];   // [8,3,2048]
  const float* win = (const float*)d_in[2];   // [8,2048]
  float* out = (float*)d_out;                 // 72 (Rs) + 24 (ts)

  char* ws = (char*)d_ws;
  float* seeds = (float*)(ws + 0);            // 8*1024*8 f32      = 262144 B
  float* Rt    = (float*)(ws + 262144);       // 8*1024*12 f32     = 393216 B
  float* w     = (float*)(ws + 655360);       // 8*2048 f32        =  65536 B
  float* logw  = (float*)(ws + 720896);       // 8*2048 f32        =  65536 B
  int*   nn    = (int*)  (ws + 786432);       // 8*1024*32 i32     = 1048576 B
  int*   fit   = (int*)  (ws + 1835008);      // 8192 i32          =  32768 B
  float* dist  = (float*)(ws + 1867776);      // 1 f32

  // JAX key derivation on host (pure arithmetic; graph-capture safe).
  // key(42) = [0,42]; key_it = fold_in = tf(key,(0,it)); then split per RBMODE.
  uint32_t k1a[10], k1b[10], k2a[10], k2b[10];
  for (int it = 0; it < 10; ++it){
    uint32_t fa, fb;
    tf2x32(0u, 42u, 0u, (uint32_t)it, fa, fb);
#if RBMODE == 0
    tf2x32(fa, fb, 0u, 0u, k1a[it], k1b[it]);   // foldlike split
    tf2x32(fa, fb, 0u, 1u, k2a[it], k2b[it]);
#else
    uint32_t a0, a1, b0, b1;
    tf2x32(fa, fb, 0u, 2u, a0, a1);             // original split: iota(4) halves
    tf2x32(fa, fb, 1u, 3u, b0, b1);
    k1a[it] = a0; k1b[it] = b0; k2a[it] = a1; k2b[it] = b1;
#endif
  }

  ghv_softmax<<<NB, 256, 0, stream>>>(win, w, logw);
  for (int it = 0; it < 10; ++it){
    ghv_seed<<<NB, 1024, 0, stream>>>(src, tgt, w, logw, seeds, k1a[it], k1b[it]);
    ghv_nn<<<dim3(NS, NB), 512, 0, stream>>>(seeds, nn, k2a[it], k2b[it]);
    ghv_kabsch<<<(NB*NS + 255)/256, 256, 0, stream>>>(seeds, nn, Rt);
    ghv_fitness<<<NB*NS, 256, 0, stream>>>(src, tgt, Rt, fit);
    ghv_select<<<1, 512, 0, stream>>>(Rt, fit, dist, out, (it == 0) ? 1 : 0);
  }
}

// Round 2
// 1832.530 us; speedup vs baseline: 1.9072x; 1.9072x over previous
//
#include <hip/hip_runtime.h>
#include <stdint.h>
#include <math.h>

// Match XLA-CPU's unfused mul/add on threshold-critical math.
#pragma clang fp contract(off)

#define RBMODE 0

#define NB   8
#define NPTS 2048
#define NS   1024
#define NG   30

typedef unsigned long long ull;

// ---------------- threefry2x32 (Random123 / JAX, 20 rounds) ----------------
__host__ __device__ __forceinline__ uint32_t rotl32(uint32_t x, int r){
  return (x << r) | (x >> (32 - r));
}
__host__ __device__ __forceinline__ void tf2x32(uint32_t k0, uint32_t k1,
                                                uint32_t x0, uint32_t x1,
                                                uint32_t& o0, uint32_t& o1){
  uint32_t k2 = k0 ^ k1 ^ 0x1BD11BDAu;
  x0 += k0; x1 += k1;
#define TFR(r) { x0 += x1; x1 = rotl32(x1, (r)); x1 ^= x0; }
  TFR(13) TFR(15) TFR(26) TFR(6)
  x0 += k1; x1 += k2 + 1u;
  TFR(17) TFR(29) TFR(16) TFR(24)
  x0 += k2; x1 += k0 + 2u;
  TFR(13) TFR(15) TFR(26) TFR(6)
  x0 += k0; x1 += k1 + 3u;
  TFR(17) TFR(29) TFR(16) TFR(24)
  x0 += k1; x1 += k2 + 4u;
  TFR(13) TFR(15) TFR(26) TFR(6)
  x0 += k2; x1 += k0 + 5u;
#undef TFR
  o0 = x0; o1 = x1;
}

__device__ __forceinline__ uint32_t rand_bits(uint32_t k0, uint32_t k1, uint32_t e){
  uint32_t o0, o1; tf2x32(k0, k1, 0u, e, o0, o1);
  return o0 ^ o1;
}

// jax.random.uniform(minval=1e-9, maxval=1.0) -> gumbel
__device__ __forceinline__ float gumbel_from(uint32_t bits){
  float f = __uint_as_float((bits >> 9) | 0x3f800000u) - 1.0f;  // [0,1)
  float u = fmaxf(1e-9f, f + 1e-9f);
  return -logf(-logf(u));
}

// ---------------- sort keys: (value desc, index asc) ----------------
__device__ __forceinline__ ull packkey(float v, uint32_t idx){
  uint32_t u = __float_as_uint(v);
  u = (u & 0x80000000u) ? ~u : (u | 0x80000000u);
  return ((ull)u << 32) | (ull)(0xFFFFFFFFu - idx);
}
__device__ __forceinline__ uint32_t unpackidx(ull k){
  return 0xFFFFFFFFu - (uint32_t)(k & 0xFFFFFFFFull);
}

__device__ __forceinline__ void bitonic_desc(ull* a, int M, int t, int T){
  for (int k = 2; k <= M; k <<= 1){
    for (int j = k >> 1; j > 0; j >>= 1){
      for (int i = t; i < M; i += T){
        int ixj = i ^ j;
        if (ixj > i){
          ull ai = a[i], aj = a[ixj];
          bool desc = ((i & k) == 0);
          if (desc ? (ai < aj) : (ai > aj)){ a[i] = aj; a[ixj] = ai; }
        }
      }
      __syncthreads();
    }
  }
}

// -------- wave-level (64-lane) register bitonic helpers, u64 keys --------
__device__ __forceinline__ ull shfl_xor_u64(ull x, int mask){
  return (ull)__shfl_xor((long long)x, mask, 64);
}
__device__ __forceinline__ ull shfl_u64(ull x, int src){
  return (ull)__shfl((long long)x, src, 64);
}

// Sort each 32-lane half of the wave descending (independent halves).
__device__ __forceinline__ ull sort32_desc(ull key, int l){
  int i = l & 31;
#pragma unroll
  for (int k = 2; k <= 16; k <<= 1){
#pragma unroll
    for (int j = k >> 1; j > 0; j >>= 1){
      ull other = shfl_xor_u64(key, j);
      bool up = ((l & j) == 0);
      bool take_max = (((i & k) == 0) == up);
      bool omax = other > key;
      key = (take_max == omax) ? other : key;
    }
  }
#pragma unroll
  for (int j = 16; j > 0; j >>= 1){
    ull other = shfl_xor_u64(key, j);
    bool up = ((l & j) == 0);
    bool omax = other > key;
    key = (up == omax) ? other : key;   // descending region
  }
  return key;
}

// Bitonic merge of a 64-lane bitonic sequence into descending order.
__device__ __forceinline__ ull merge64_desc(ull key, int l){
#pragma unroll
  for (int j = 32; j > 0; j >>= 1){
    ull other = shfl_xor_u64(key, j);
    bool up = ((l & j) == 0);
    bool omax = other > key;
    key = (up == omax) ? other : key;
  }
  return key;
}

// Given lower half sorted desc and upper half sorted desc, produce full 64
// sorted desc (reverse upper, then merge). Lanes 0..31 end with top-32.
__device__ __forceinline__ ull mergehalves_desc(ull key, int l){
  ull rev = shfl_xor_u64(key, 31);
  if (l >= 32) key = rev;
  return merge64_desc(key, l);
}

// ---------------- kernel 0: nan/inf cleanup + softmax + log ----------------
__global__ __launch_bounds__(256) void ghv_softmax(const float* __restrict__ win,
                                                   float* __restrict__ w,
                                                   float* __restrict__ logw){
  int b = blockIdx.x, t = threadIdx.x;
  __shared__ float sh[NPTS];
  __shared__ float red[4];
  __shared__ float bcast;
  for (int n = t; n < NPTS; n += 256){
    float x = win[b*NPTS + n];
    if (isnan(x)) x = 1e-7f;
    if (isinf(x)) x = 1.0f;
    sh[n] = x;
  }
  __syncthreads();
  float m = -INFINITY;
  for (int n = t; n < NPTS; n += 256) m = fmaxf(m, sh[n]);
  for (int off = 32; off >= 1; off >>= 1) m = fmaxf(m, __shfl_down(m, off));
  if ((t & 63) == 0) red[t >> 6] = m;
  __syncthreads();
  if (t == 0) bcast = fmaxf(fmaxf(red[0], red[1]), fmaxf(red[2], red[3]));
  __syncthreads();
  float mx = bcast;
  float ss = 0.0f;
  for (int n = t; n < NPTS; n += 256){ float e = expf(sh[n] - mx); sh[n] = e; ss += e; }
  for (int off = 32; off >= 1; off >>= 1) ss += __shfl_down(ss, off);
  if ((t & 63) == 0) red[t >> 6] = ss;
  __syncthreads();
  if (t == 0) bcast = red[0] + red[1] + red[2] + red[3];
  __syncthreads();
  float tot = bcast;
  for (int n = t; n < NPTS; n += 256){
    float wv = sh[n] / tot;
    w[b*NPTS + n] = wv;
    logw[b*NPTS + n] = logf(wv);
  }
}

// ---------------- kernel 1: seed gumbel top-1024 + gather ----------------
__global__ __launch_bounds__(1024) void ghv_seed(const float* __restrict__ src,
                                                 const float* __restrict__ tgt,
                                                 const float* __restrict__ w,
                                                 const float* __restrict__ logw,
                                                 float* __restrict__ seeds,
                                                 uint32_t k0, uint32_t k1){
  __shared__ ull keys[NPTS];
  int b = blockIdx.x, t = threadIdx.x;
  for (int n = t; n < NPTS; n += 1024){
    uint32_t bits = rand_bits(k0, k1, (uint32_t)(b*NPTS + n));
    float v = logw[b*NPTS + n] + gumbel_from(bits);
    keys[n] = packkey(v, (uint32_t)n);
  }
  __syncthreads();
  bitonic_desc(keys, NPTS, t, 1024);
  int s = t;  // first NS entries, in top_k order
  uint32_t idx = unpackidx(keys[s]);
  const float* sb = src + b*3*NPTS;
  const float* tb = tgt + b*3*NPTS;
  float* sp = seeds + (size_t)((b << 10) + s) * 8;
  sp[0] = sb[idx]; sp[1] = sb[NPTS + idx]; sp[2] = sb[2*NPTS + idx];
  sp[3] = tb[idx]; sp[4] = tb[NPTS + idx]; sp[5] = tb[2*NPTS + idx];
  sp[6] = w[b*NPTS + idx]; sp[7] = 0.0f;
}

// ---------------- kernel 2: consensus + gumbel top-30 per (b,s) row ----------------
// In-register wave-level top-32 selection; only the 8->4->2->1 tree uses LDS.
__global__ __launch_bounds__(512) void ghv_nn(const float* __restrict__ seeds,
                                              int* __restrict__ nn,
                                              uint32_t k0, uint32_t k1){
  __shared__ float cons_sh[NS];
  __shared__ float red[8];
  __shared__ float srow[8];
  __shared__ float rowsum_sh;
  __shared__ ull sbuf[256];   // 8 segments x 32
  __shared__ ull sbuf2[128];  // 4 segments x 32
  int s = blockIdx.x, b = blockIdx.y, t = threadIdx.x;
  int wv = t >> 6, l = t & 63;
  if (t < 8) srow[t] = seeds[(size_t)((b << 10) + s)*8 + t];
  __syncthreads();
  float part = 0.0f;
#pragma unroll
  for (int q = 0; q < 2; ++q){
    int j = t + q*512;
    const float4* jp = (const float4*)(seeds + (size_t)((b << 10) + j)*8);
    float4 p0 = jp[0], p1 = jp[1];
    float dxs = srow[0]-p0.x, dys = srow[1]-p0.y, dzs = srow[2]-p0.z;
    float ds  = sqrtf(dxs*dxs + dys*dys + dzs*dzs);
    float dxc = srow[3]-p0.w, dyc = srow[4]-p1.x, dzc = srow[5]-p1.y;
    float dc  = sqrtf(dxc*dxc + dyc*dyc + dzc*dzc);
    float diff = ds - dc;
    float cons = expf((-(diff*diff)) / 0.01f);   // -(d**2)/SIGMA
    cons = fmaxf(cons, 0.1f);                    // clip(., 0.1, None)
    cons_sh[j] = cons;
    part += cons;
  }
  for (int off = 32; off >= 1; off >>= 1) part += __shfl_down(part, off);
  if ((t & 63) == 0) red[t >> 6] = part;
  __syncthreads();
  if (t == 0){ float tot = 0.0f; for (int i = 0; i < 8; ++i) tot += red[i]; rowsum_sh = tot; }
  __syncthreads();
  float rowsum = rowsum_sh;

  // ---- per-wave top-32 over its 128 elements, all in registers ----
  ull top[2];
#pragma unroll
  for (int p = 0; p < 2; ++p){
    int e = (wv << 7) + (p << 6) + l;
    uint32_t eflat = (uint32_t)((b << 20) + (s << 10) + e);
    uint32_t bits = rand_bits(k0, k1, eflat);
    float vkey = logf(cons_sh[e] / rowsum) + gumbel_from(bits);
    ull key = packkey(vkey, (uint32_t)e);
    key = sort32_desc(key, l);      // each 32-half sorted desc
    key = mergehalves_desc(key, l); // lanes 0..31 = top-32 of this 64
    top[p] = key;
  }
  // combine the two passes: lanes 0..31 keep top[0]; lanes 32..63 take
  // top[1] reversed (source lane 63-l in 0..31), then merge.
  ull keyB = shfl_u64(top[1], 63 - l);
  ull key = (l < 32) ? top[0] : keyB;
  key = merge64_desc(key, l);       // lanes 0..31 = wave top-32

  if (l < 32) sbuf[(wv << 5) + l] = key;
  __syncthreads();

  // round 1: 8 segments -> 4
  if (wv < 4){
    ull k2 = (l < 32) ? sbuf[(wv << 6) + l] : sbuf[(wv << 6) + 95 - l];
    k2 = merge64_desc(k2, l);
    if (l < 32) sbuf2[(wv << 5) + l] = k2;
  }
  __syncthreads();
  // round 2: 4 -> 2
  if (wv < 2){
    ull k2 = (l < 32) ? sbuf2[(wv << 6) + l] : sbuf2[(wv << 6) + 95 - l];
    k2 = merge64_desc(k2, l);
    if (l < 32) sbuf[(wv << 5) + l] = k2;
  }
  __syncthreads();
  // round 3: 2 -> 1, emit
  if (wv == 0){
    ull k2 = (l < 32) ? sbuf[l] : sbuf[95 - l];
    k2 = merge64_desc(k2, l);
    if (l < 32){
      int vidx = (l < NG) ? (int)unpackidx(k2) : 0;
      nn[(size_t)((b << 10) + s)*32 + l] = vidx;
    }
  }
}

// ---------------- kernel 3: weighted Kabsch + 3x3 SVD (double) ----------------
__global__ __launch_bounds__(256) void ghv_kabsch(const float* __restrict__ seeds,
                                                  const int* __restrict__ nn,
                                                  float* __restrict__ Rt){
  int id = blockIdx.x*256 + threadIdx.x;
  if (id >= NB*NS) return;
  int b = id >> 10;
  const int* nnp = nn + (size_t)id*32;

  float sxs=0, sys=0, szs=0, cxs=0, cys=0, czs=0, wsum=0;
  for (int g = 0; g < NG; ++g){
    int j = nnp[g];
    const float4* jp = (const float4*)(seeds + (size_t)((b << 10) + j)*8);
    float4 p0 = jp[0], p1 = jp[1];
    sxs += p0.x; sys += p0.y; szs += p0.z;
    cxs += p0.w; cys += p1.x; czs += p1.y;
    wsum += p1.z;
  }
  float msx = sxs/30.0f, msy = sys/30.0f, msz = szs/30.0f;
  float mcx = cxs/30.0f, mcy = cys/30.0f, mcz = czs/30.0f;

  float Hf[9] = {0,0,0,0,0,0,0,0,0};
  for (int g = 0; g < NG; ++g){
    int j = nnp[g];
    const float4* jp = (const float4*)(seeds + (size_t)((b << 10) + j)*8);
    float4 p0 = jp[0], p1 = jp[1];
    float wg = p1.z / wsum;
    float a0 = p0.x - msx, a1 = p0.y - msy, a2 = p0.z - msz;
    float b0 = p0.w - mcx, b1 = p1.x - mcy, b2 = p1.y - mcz;
    float a0w = a0*wg, a1w = a1*wg, a2w = a2*wg;
    Hf[0] += a0w*b0; Hf[1] += a0w*b1; Hf[2] += a0w*b2;
    Hf[3] += a1w*b0; Hf[4] += a1w*b1; Hf[5] += a1w*b2;
    Hf[6] += a2w*b0; Hf[7] += a2w*b1; Hf[8] += a2w*b2;
  }

  double H[9]; for (int i = 0; i < 9; ++i) H[i] = (double)Hf[i];
  double A[3][3];
  A[0][0] = H[0]*H[0] + H[3]*H[3] + H[6]*H[6];
  A[0][1] = H[0]*H[1] + H[3]*H[4] + H[6]*H[7];
  A[0][2] = H[0]*H[2] + H[3]*H[5] + H[6]*H[8];
  A[1][1] = H[1]*H[1] + H[4]*H[4] + H[7]*H[7];
  A[1][2] = H[1]*H[2] + H[4]*H[5] + H[7]*H[8];
  A[2][2] = H[2]*H[2] + H[5]*H[5] + H[8]*H[8];
  A[1][0] = A[0][1]; A[2][0] = A[0][2]; A[2][1] = A[1][2];
  double V[3][3] = {{1,0,0},{0,1,0},{0,0,1}};
  for (int sw = 0; sw < 12; ++sw){
    for (int p = 0; p < 2; ++p){
      for (int q = p+1; q < 3; ++q){
        double apq = A[p][q];
        if (fabs(apq) > 1e-300){
          double th = (A[q][q] - A[p][p]) / (2.0*apq);
          double tt = copysign(1.0, th) / (fabs(th) + sqrt(1.0 + th*th));
          double c  = 1.0 / sqrt(1.0 + tt*tt), sn = tt*c;
          int r = 3 - p - q;
          double app = A[p][p], aqq = A[q][q];
          double arp = A[r][p], arq = A[r][q];
          A[p][p] = app - tt*apq;
          A[q][q] = aqq + tt*apq;
          A[p][q] = 0.0; A[q][p] = 0.0;
          A[r][p] = c*arp - sn*arq; A[p][r] = A[r][p];
          A[r][q] = sn*arp + c*arq; A[q][r] = A[r][q];
          for (int kk = 0; kk < 3; ++kk){
            double vp = V[kk][p], vq = V[kk][q];
            V[kk][p] = c*vp - sn*vq;
            V[kk][q] = sn*vp + c*vq;
          }
        }
      }
    }
  }
  int o0 = 0, o1 = 1, o2 = 2;
  double l0 = A[0][0], l1 = A[1][1], l2 = A[2][2];
  double tmp; int ti;
  if (l0 < l1){ tmp=l0; l0=l1; l1=tmp; ti=o0; o0=o1; o1=ti; }
  if (l0 < l2){ tmp=l0; l0=l2; l2=tmp; ti=o0; o0=o2; o2=ti; }
  if (l1 < l2){ tmp=l1; l1=l2; l2=tmp; ti=o1; o1=o2; o2=ti; }
  double v0[3] = {V[0][o0], V[1][o0], V[2][o0]};
  double v1[3] = {V[0][o1], V[1][o1], V[2][o1]};
  double v2[3] = {V[0][o2], V[1][o2], V[2][o2]};

  double u0[3], u1[3], u2[3];
  for (int i = 0; i < 3; ++i) u0[i] = H[i*3+0]*v0[0] + H[i*3+1]*v0[1] + H[i*3+2]*v0[2];
  double n0 = sqrt(u0[0]*u0[0] + u0[1]*u0[1] + u0[2]*u0[2]);
  if (n0 > 1e-150){ u0[0]/=n0; u0[1]/=n0; u0[2]/=n0; }
  else { u0[0]=1; u0[1]=0; u0[2]=0; }
  for (int i = 0; i < 3; ++i) u1[i] = H[i*3+0]*v1[0] + H[i*3+1]*v1[1] + H[i*3+2]*v1[2];
  double d01 = u0[0]*u1[0] + u0[1]*u1[1] + u0[2]*u1[2];
  for (int i = 0; i < 3; ++i) u1[i] -= d01*u0[i];
  double n1 = sqrt(u1[0]*u1[0] + u1[1]*u1[1] + u1[2]*u1[2]);
  if (n1 > 1e-150){ u1[0]/=n1; u1[1]/=n1; u1[2]/=n1; }
  else {
    double ax = fabs(u0[0]), ay = fabs(u0[1]), az = fabs(u0[2]);
    double e[3] = {0,0,0};
    if (ax <= ay && ax <= az) e[0] = 1; else if (ay <= az) e[1] = 1; else e[2] = 1;
    double de = u0[0]*e[0] + u0[1]*e[1] + u0[2]*e[2];
    for (int i = 0; i < 3; ++i) u1[i] = e[i] - de*u0[i];
    double nn1 = sqrt(u1[0]*u1[0] + u1[1]*u1[1] + u1[2]*u1[2]);
    for (int i = 0; i < 3; ++i) u1[i] /= nn1;
  }
  u2[0] = u0[1]*u1[2] - u0[2]*u1[1];
  u2[1] = u0[2]*u1[0] - u0[0]*u1[2];
  u2[2] = u0[0]*u1[1] - u0[1]*u1[0];
  double detV = v0[0]*(v1[1]*v2[2] - v1[2]*v2[1])
              - v0[1]*(v1[0]*v2[2] - v1[2]*v2[0])
              + v0[2]*(v1[0]*v2[1] - v1[1]*v2[0]);
  float Rf[9];
  for (int i = 0; i < 3; ++i)
    for (int j = 0; j < 3; ++j)
      Rf[i*3+j] = (float)(v0[i]*u0[j] + v1[i]*u1[j] + detV*(v2[i]*u2[j]));
  float tx = -(Rf[0]*msx + Rf[1]*msy + Rf[2]*msz) + mcx;
  float ty = -(Rf[3]*msx + Rf[4]*msy + Rf[5]*msz) + mcy;
  float tz = -(Rf[6]*msx + Rf[7]*msy + Rf[8]*msz) + mcz;
  float* o = Rt + (size_t)id*12;
  for (int i = 0; i < 9; ++i) o[i] = Rf[i];
  o[9] = tx; o[10] = ty; o[11] = tz;
}

// ---------------- kernel 4: fitness = #(||R src + t - tgt|| < 0.1) ----------------
__global__ __launch_bounds__(256) void ghv_fitness(const float* __restrict__ src,
                                                   const float* __restrict__ tgt,
                                                   const float* __restrict__ Rt,
                                                   int* __restrict__ fit){
  int id = blockIdx.x;
  int b = id >> 10;
  const float* rt = Rt + (size_t)id*12;
  float R0 = rt[0], R1 = rt[1], R2 = rt[2];
  float R3 = rt[3], R4 = rt[4], R5 = rt[5];
  float R6 = rt[6], R7 = rt[7], R8 = rt[8];
  float t0 = rt[9], t1 = rt[10], t2 = rt[11];
  const float* sb = src + b*3*NPTS;
  const float* tb = tgt + b*3*NPTS;
  int cnt = 0;
  for (int n = threadIdx.x; n < NPTS; n += 256){
    float x = sb[n], y = sb[n + NPTS], z = sb[n + 2*NPTS];
    float px = R0*x + R1*y + R2*z + t0;
    float py = R3*x + R4*y + R5*z + t1;
    float pz = R6*x + R7*y + R8*z + t2;
    float dx = px - tb[n], dy = py - tb[n + NPTS], dz = pz - tb[n + 2*NPTS];
    float l2 = sqrtf(dx*dx + dy*dy + dz*dz);
    cnt += (l2 < 0.1f) ? 1 : 0;
  }
  for (int off = 32; off >= 1; off >>= 1) cnt += __shfl_down(cnt, off);
  __shared__ int ws4[4];
  if ((threadIdx.x & 63) == 0) ws4[threadIdx.x >> 6] = cnt;
  __syncthreads();
  if (threadIdx.x == 0) fit[id] = ws4[0] + ws4[1] + ws4[2] + ws4[3];
}

// ---------------- kernel 5: argmax / vv / select-best-iteration ----------------
__global__ __launch_bounds__(512) void ghv_select(const float* __restrict__ Rt,
                                                  const int* __restrict__ fit,
                                                  float* __restrict__ dist_ws,
                                                  float* __restrict__ out,
                                                  int first){
  __shared__ int mc[8], mi[8];
  __shared__ int flag;
  int t = threadIdx.x;
  int b = t >> 6, lane = t & 63;
  int bc = -1, bi = 0;
  for (int s = lane; s < NS; s += 64){
    int c = fit[(b << 10) + s];
    if (c > bc){ bc = c; bi = s; }
  }
  for (int off = 32; off >= 1; off >>= 1){
    int oc = __shfl_down(bc, off);
    int oi = __shfl_down(bi, off);
    if (oc > bc || (oc == bc && oi < bi)){ bc = oc; bi = oi; }
  }
  if (lane == 0){ mc[b] = bc; mi[b] = bi; }
  __syncthreads();
  if (t == 0){
    int sum = 0; for (int i = 0; i < 8; ++i) sum += mc[i];
    float vv = (float)sum / 16384.0f;
    float dist = first ? 1e8f : dist_ws[0];
    int better = (vv < dist) ? 1 : 0;
    if (better) dist_ws[0] = vv;
    flag = better;
  }
  __syncthreads();
  if (flag){
    for (int i = t; i < 96; i += 512){
      float v;
      if (i < 72){
        int bb = i / 9, k = i % 9;
        v = Rt[(size_t)((bb << 10) + mi[bb])*12 + k];
      } else {
        int ii = i - 72; int bb = ii / 3, k = ii % 3;
        v = Rt[(size_t)((bb << 10) + mi[bb])*12 + 9 + k];
      }
      out[i] = v;
    }
  }
}

// ---------------- host ----------------
extern "C" void kernel_launch(void* const* d_in, const int* in_sizes, int n_in,
                              void* d_out, int out_size, void* d_ws, size_t ws_size,
                              hipStream_t stream){
  const float* src = (const float*)d_in[0];
  const float* tgt = (const float*)d_in[1];
  const float* win = (const float*)d_in[2];
  float* out = (float*)d_out;

  char* ws = (char*)d_ws;
  float* seeds = (float*)(ws + 0);            // 262144 B
  float* Rt    = (float*)(ws + 262144);       // 393216 B
  float* w     = (float*)(ws + 655360);       // 65536 B
  float* logw  = (float*)(ws + 720896);       // 65536 B
  int*   nn    = (int*)  (ws + 786432);       // 1048576 B
  int*   fit   = (int*)  (ws + 1835008);      // 32768 B
  float* dist  = (float*)(ws + 1867776);      // 4 B

  uint32_t k1a[10], k1b[10], k2a[10], k2b[10];
  for (int it = 0; it < 10; ++it){
    uint32_t fa, fb;
    tf2x32(0u, 42u, 0u, (uint32_t)it, fa, fb);
    tf2x32(fa, fb, 0u, 0u, k1a[it], k1b[it]);
    tf2x32(fa, fb, 0u, 1u, k2a[it], k2b[it]);
  }

  ghv_softmax<<<NB, 256, 0, stream>>>(win, w, logw);
  for (int it = 0; it < 10; ++it){
    ghv_seed<<<NB, 1024, 0, stream>>>(src, tgt, w, logw, seeds, k1a[it], k1b[it]);
    ghv_nn<<<dim3(NS, NB), 512, 0, stream>>>(seeds, nn, k2a[it], k2b[it]);
    ghv_kabsch<<<(NB*NS + 255)/256, 256, 0, stream>>>(seeds, nn, Rt);
    ghv_fitness<<<NB*NS, 256, 0, stream>>>(src, tgt, Rt, fit);
    ghv_select<<<1, 512, 0, stream>>>(Rt, fit, dist, out, (it == 0) ? 1 : 0);
  }
}

// Round 3
// 1197.089 us; speedup vs baseline: 2.9196x; 1.5308x over previous
//
#include <hip/hip_runtime.h>
#include <stdint.h>
#include <math.h>

// Match XLA-CPU's unfused mul/add on threshold-critical math.
#pragma clang fp contract(off)

#define NB    8
#define NPTS  2048
#define NS    1024
#define NG    30
#define NITER 10

typedef unsigned long long ull;

// ---------------- threefry2x32 (Random123 / JAX, 20 rounds) ----------------
__host__ __device__ __forceinline__ uint32_t rotl32(uint32_t x, int r){
  return (x << r) | (x >> (32 - r));
}
__host__ __device__ __forceinline__ void tf2x32(uint32_t k0, uint32_t k1,
                                                uint32_t x0, uint32_t x1,
                                                uint32_t& o0, uint32_t& o1){
  uint32_t k2 = k0 ^ k1 ^ 0x1BD11BDAu;
  x0 += k0; x1 += k1;
#define TFR(r) { x0 += x1; x1 = rotl32(x1, (r)); x1 ^= x0; }
  TFR(13) TFR(15) TFR(26) TFR(6)
  x0 += k1; x1 += k2 + 1u;
  TFR(17) TFR(29) TFR(16) TFR(24)
  x0 += k2; x1 += k0 + 2u;
  TFR(13) TFR(15) TFR(26) TFR(6)
  x0 += k0; x1 += k1 + 3u;
  TFR(17) TFR(29) TFR(16) TFR(24)
  x0 += k1; x1 += k2 + 4u;
  TFR(13) TFR(15) TFR(26) TFR(6)
  x0 += k2; x1 += k0 + 5u;
#undef TFR
  o0 = x0; o1 = x1;
}

// partitionable threefry: bits[e] = o0^o1 of tf(key,(0,e))
__device__ __forceinline__ uint32_t rand_bits(uint32_t k0, uint32_t k1, uint32_t e){
  uint32_t o0, o1; tf2x32(k0, k1, 0u, e, o0, o1);
  return o0 ^ o1;
}

// split(fold_in(key(42), it)): k_i = tf(folded, (0, i)), i in {0,1}
__device__ __forceinline__ void derive_key(int it, uint32_t which,
                                           uint32_t& a, uint32_t& b){
  uint32_t fa, fb;
  tf2x32(0u, 42u, 0u, (uint32_t)it, fa, fb);
  tf2x32(fa, fb, 0u, which, a, b);
}

// jax.random.uniform(minval=1e-9, maxval=1.0) -> gumbel
__device__ __forceinline__ float gumbel_from(uint32_t bits){
  float f = __uint_as_float((bits >> 9) | 0x3f800000u) - 1.0f;  // [0,1)
  float u = fmaxf(1e-9f, f + 1e-9f);
  return -logf(-logf(u));
}

// ---------------- sort keys: (value desc, index asc) ----------------
__device__ __forceinline__ ull packkey(float v, uint32_t idx){
  uint32_t u = __float_as_uint(v);
  u = (u & 0x80000000u) ? ~u : (u | 0x80000000u);
  return ((ull)u << 32) | (ull)(0xFFFFFFFFu - idx);
}
__device__ __forceinline__ uint32_t unpackidx(ull k){
  return 0xFFFFFFFFu - (uint32_t)(k & 0xFFFFFFFFull);
}

__device__ __forceinline__ void bitonic_desc(ull* a, int M, int t, int T){
  for (int k = 2; k <= M; k <<= 1){
    for (int j = k >> 1; j > 0; j >>= 1){
      for (int i = t; i < M; i += T){
        int ixj = i ^ j;
        if (ixj > i){
          ull ai = a[i], aj = a[ixj];
          bool desc = ((i & k) == 0);
          if (desc ? (ai < aj) : (ai > aj)){ a[i] = aj; a[ixj] = ai; }
        }
      }
      __syncthreads();
    }
  }
}

// -------- wave-level (64-lane) register bitonic helpers, u64 keys --------
__device__ __forceinline__ ull shfl_xor_u64(ull x, int mask){
  return (ull)__shfl_xor((long long)x, mask, 64);
}
__device__ __forceinline__ ull shfl_u64(ull x, int src){
  return (ull)__shfl((long long)x, src, 64);
}

__device__ __forceinline__ ull sort32_desc(ull key, int l){
  int i = l & 31;
#pragma unroll
  for (int k = 2; k <= 16; k <<= 1){
#pragma unroll
    for (int j = k >> 1; j > 0; j >>= 1){
      ull other = shfl_xor_u64(key, j);
      bool up = ((l & j) == 0);
      bool take_max = (((i & k) == 0) == up);
      bool omax = other > key;
      key = (take_max == omax) ? other : key;
    }
  }
#pragma unroll
  for (int j = 16; j > 0; j >>= 1){
    ull other = shfl_xor_u64(key, j);
    bool up = ((l & j) == 0);
    bool omax = other > key;
    key = (up == omax) ? other : key;
  }
  return key;
}

__device__ __forceinline__ ull merge64_desc(ull key, int l){
#pragma unroll
  for (int j = 32; j > 0; j >>= 1){
    ull other = shfl_xor_u64(key, j);
    bool up = ((l & j) == 0);
    bool omax = other > key;
    key = (up == omax) ? other : key;
  }
  return key;
}

__device__ __forceinline__ ull mergehalves_desc(ull key, int l){
  ull rev = shfl_xor_u64(key, 31);
  if (l >= 32) key = rev;
  return merge64_desc(key, l);
}

// ---------------- kernel 0: nan/inf cleanup + softmax + log ----------------
__global__ __launch_bounds__(256) void ghv_softmax(const float* __restrict__ win,
                                                   float* __restrict__ w,
                                                   float* __restrict__ logw){
  int b = blockIdx.x, t = threadIdx.x;
  __shared__ float sh[NPTS];
  __shared__ float red[4];
  __shared__ float bcast;
  for (int n = t; n < NPTS; n += 256){
    float x = win[b*NPTS + n];
    if (isnan(x)) x = 1e-7f;
    if (isinf(x)) x = 1.0f;
    sh[n] = x;
  }
  __syncthreads();
  float m = -INFINITY;
  for (int n = t; n < NPTS; n += 256) m = fmaxf(m, sh[n]);
  for (int off = 32; off >= 1; off >>= 1) m = fmaxf(m, __shfl_down(m, off));
  if ((t & 63) == 0) red[t >> 6] = m;
  __syncthreads();
  if (t == 0) bcast = fmaxf(fmaxf(red[0], red[1]), fmaxf(red[2], red[3]));
  __syncthreads();
  float mx = bcast;
  float ss = 0.0f;
  for (int n = t; n < NPTS; n += 256){ float e = expf(sh[n] - mx); sh[n] = e; ss += e; }
  for (int off = 32; off >= 1; off >>= 1) ss += __shfl_down(ss, off);
  if ((t & 63) == 0) red[t >> 6] = ss;
  __syncthreads();
  if (t == 0) bcast = red[0] + red[1] + red[2] + red[3];
  __syncthreads();
  float tot = bcast;
  for (int n = t; n < NPTS; n += 256){
    float wv = sh[n] / tot;
    w[b*NPTS + n] = wv;
    logw[b*NPTS + n] = logf(wv);
  }
}

// ---------------- kernel 1: seed gumbel top-1024 + gather ----------------
// grid (NB, 1, nz); slot = seq ? 0 : it
__global__ __launch_bounds__(1024) void ghv_seed(const float* __restrict__ src,
                                                 const float* __restrict__ tgt,
                                                 const float* __restrict__ w,
                                                 const float* __restrict__ logw,
                                                 float* __restrict__ seeds,
                                                 int it0, int seq){
  __shared__ ull keys[NPTS];
  __shared__ uint32_t kk[2];
  int b = blockIdx.x, t = threadIdx.x;
  int it = it0 + blockIdx.z;
  int slot = seq ? 0 : it;
  if (t == 0){ derive_key(it, 0u, kk[0], kk[1]); }
  __syncthreads();
  uint32_t k0 = kk[0], k1 = kk[1];
  for (int n = t; n < NPTS; n += 1024){
    uint32_t bits = rand_bits(k0, k1, (uint32_t)(b*NPTS + n));
    float v = logw[b*NPTS + n] + gumbel_from(bits);
    keys[n] = packkey(v, (uint32_t)n);
  }
  __syncthreads();
  bitonic_desc(keys, NPTS, t, 1024);
  int s = t;
  uint32_t idx = unpackidx(keys[s]);
  const float* sb = src + b*3*NPTS;
  const float* tb = tgt + b*3*NPTS;
  float* sp = seeds + (size_t)slot*(NB*NS*8) + (size_t)((b << 10) + s) * 8;
  sp[0] = sb[idx]; sp[1] = sb[NPTS + idx]; sp[2] = sb[2*NPTS + idx];
  sp[3] = tb[idx]; sp[4] = tb[NPTS + idx]; sp[5] = tb[2*NPTS + idx];
  sp[6] = w[b*NPTS + idx]; sp[7] = 0.0f;
}

// ---------------- kernel 2: consensus + gumbel top-30 per (b,s) row ----------------
// grid (NS, NB, nz)
__global__ __launch_bounds__(512) void ghv_nn(const float* __restrict__ seeds,
                                              unsigned short* __restrict__ nnb,
                                              int it0, int seq){
  __shared__ float cons_sh[NS];
  __shared__ float red[8];
  __shared__ float srow[8];
  __shared__ float rowsum_sh;
  __shared__ uint32_t kk[2];
  __shared__ ull sbuf[256];
  __shared__ ull sbuf2[128];
  int s = blockIdx.x, b = blockIdx.y, t = threadIdx.x;
  int it = it0 + blockIdx.z;
  int slot = seq ? 0 : it;
  const float* sdat = seeds + (size_t)slot*(NB*NS*8);
  int wv = t >> 6, l = t & 63;
  if (t < 8) srow[t] = sdat[(size_t)((b << 10) + s)*8 + t];
  if (t == 0){ derive_key(it, 1u, kk[0], kk[1]); }
  __syncthreads();
  uint32_t k0 = kk[0], k1 = kk[1];
  float part = 0.0f;
#pragma unroll
  for (int q = 0; q < 2; ++q){
    int j = t + q*512;
    const float4* jp = (const float4*)(sdat + (size_t)((b << 10) + j)*8);
    float4 p0 = jp[0], p1 = jp[1];
    float dxs = srow[0]-p0.x, dys = srow[1]-p0.y, dzs = srow[2]-p0.z;
    float ds  = sqrtf(dxs*dxs + dys*dys + dzs*dzs);
    float dxc = srow[3]-p0.w, dyc = srow[4]-p1.x, dzc = srow[5]-p1.y;
    float dc  = sqrtf(dxc*dxc + dyc*dyc + dzc*dzc);
    float diff = ds - dc;
    float cons = expf((-(diff*diff)) / 0.01f);
    cons = fmaxf(cons, 0.1f);
    cons_sh[j] = cons;
    part += cons;
  }
  for (int off = 32; off >= 1; off >>= 1) part += __shfl_down(part, off);
  if ((t & 63) == 0) red[t >> 6] = part;
  __syncthreads();
  if (t == 0){ float tot = 0.0f; for (int i = 0; i < 8; ++i) tot += red[i]; rowsum_sh = tot; }
  __syncthreads();
  float rowsum = rowsum_sh;

  ull top[2];
#pragma unroll
  for (int p = 0; p < 2; ++p){
    int e = (wv << 7) + (p << 6) + l;
    uint32_t eflat = (uint32_t)((b << 20) + (s << 10) + e);
    uint32_t bits = rand_bits(k0, k1, eflat);
    float vkey = logf(cons_sh[e] / rowsum) + gumbel_from(bits);
    ull key = packkey(vkey, (uint32_t)e);
    key = sort32_desc(key, l);
    key = mergehalves_desc(key, l);
    top[p] = key;
  }
  ull keyB = shfl_u64(top[1], 63 - l);
  ull key = (l < 32) ? top[0] : keyB;
  key = merge64_desc(key, l);

  if (l < 32) sbuf[(wv << 5) + l] = key;
  __syncthreads();
  if (wv < 4){
    ull k2 = (l < 32) ? sbuf[(wv << 6) + l] : sbuf[(wv << 6) + 95 - l];
    k2 = merge64_desc(k2, l);
    if (l < 32) sbuf2[(wv << 5) + l] = k2;
  }
  __syncthreads();
  if (wv < 2){
    ull k2 = (l < 32) ? sbuf2[(wv << 6) + l] : sbuf2[(wv << 6) + 95 - l];
    k2 = merge64_desc(k2, l);
    if (l < 32) sbuf[(wv << 5) + l] = k2;
  }
  __syncthreads();
  if (wv == 0){
    ull k2 = (l < 32) ? sbuf[l] : sbuf[95 - l];
    k2 = merge64_desc(k2, l);
    if (l < 32){
      unsigned short vidx = (l < NG) ? (unsigned short)unpackidx(k2) : 0;
      nnb[((size_t)slot*(NB*NS) + (size_t)((b << 10) + s))*32 + l] = vidx;
    }
  }
}

// ---------------- kernel 3: weighted Kabsch + 3x3 SVD (double) ----------------
// grid (NB*NS/64, 1, nz), block 64
__global__ __launch_bounds__(64) void ghv_kabsch(const float* __restrict__ seeds,
                                                 const unsigned short* __restrict__ nnb,
                                                 float* __restrict__ Rt,
                                                 int it0, int seq){
  int id = blockIdx.x*64 + threadIdx.x;
  int it = it0 + blockIdx.z;
  int slot = seq ? 0 : it;
  int b = id >> 10;
  const float* sdat = seeds + (size_t)slot*(NB*NS*8);
  const unsigned short* nnp = nnb + ((size_t)slot*(NB*NS) + (size_t)id)*32;

  float sxs=0, sys=0, szs=0, cxs=0, cys=0, czs=0, wsum=0;
  for (int g = 0; g < NG; ++g){
    int j = nnp[g];
    const float4* jp = (const float4*)(sdat + (size_t)((b << 10) + j)*8);
    float4 p0 = jp[0], p1 = jp[1];
    sxs += p0.x; sys += p0.y; szs += p0.z;
    cxs += p0.w; cys += p1.x; czs += p1.y;
    wsum += p1.z;
  }
  float msx = sxs/30.0f, msy = sys/30.0f, msz = szs/30.0f;
  float mcx = cxs/30.0f, mcy = cys/30.0f, mcz = czs/30.0f;

  float Hf[9] = {0,0,0,0,0,0,0,0,0};
  for (int g = 0; g < NG; ++g){
    int j = nnp[g];
    const float4* jp = (const float4*)(sdat + (size_t)((b << 10) + j)*8);
    float4 p0 = jp[0], p1 = jp[1];
    float wg = p1.z / wsum;
    float a0 = p0.x - msx, a1 = p0.y - msy, a2 = p0.z - msz;
    float b0 = p0.w - mcx, b1 = p1.x - mcy, b2 = p1.y - mcz;
    float a0w = a0*wg, a1w = a1*wg, a2w = a2*wg;
    Hf[0] += a0w*b0; Hf[1] += a0w*b1; Hf[2] += a0w*b2;
    Hf[3] += a1w*b0; Hf[4] += a1w*b1; Hf[5] += a1w*b2;
    Hf[6] += a2w*b0; Hf[7] += a2w*b1; Hf[8] += a2w*b2;
  }

  double H[9]; for (int i = 0; i < 9; ++i) H[i] = (double)Hf[i];
  double A[3][3];
  A[0][0] = H[0]*H[0] + H[3]*H[3] + H[6]*H[6];
  A[0][1] = H[0]*H[1] + H[3]*H[4] + H[6]*H[7];
  A[0][2] = H[0]*H[2] + H[3]*H[5] + H[6]*H[8];
  A[1][1] = H[1]*H[1] + H[4]*H[4] + H[7]*H[7];
  A[1][2] = H[1]*H[2] + H[4]*H[5] + H[7]*H[8];
  A[2][2] = H[2]*H[2] + H[5]*H[5] + H[8]*H[8];
  A[1][0] = A[0][1]; A[2][0] = A[0][2]; A[2][1] = A[1][2];
  double V[3][3] = {{1,0,0},{0,1,0},{0,0,1}};
  for (int sw = 0; sw < 12; ++sw){
    for (int p = 0; p < 2; ++p){
      for (int q = p+1; q < 3; ++q){
        double apq = A[p][q];
        if (fabs(apq) > 1e-300){
          double th = (A[q][q] - A[p][p]) / (2.0*apq);
          double tt = copysign(1.0, th) / (fabs(th) + sqrt(1.0 + th*th));
          double c  = 1.0 / sqrt(1.0 + tt*tt), sn = tt*c;
          int r = 3 - p - q;
          double app = A[p][p], aqq = A[q][q];
          double arp = A[r][p], arq = A[r][q];
          A[p][p] = app - tt*apq;
          A[q][q] = aqq + tt*apq;
          A[p][q] = 0.0; A[q][p] = 0.0;
          A[r][p] = c*arp - sn*arq; A[p][r] = A[r][p];
          A[r][q] = sn*arp + c*arq; A[q][r] = A[r][q];
          for (int kk = 0; kk < 3; ++kk){
            double vp = V[kk][p], vq = V[kk][q];
            V[kk][p] = c*vp - sn*vq;
            V[kk][q] = sn*vp + c*vq;
          }
        }
      }
    }
  }
  int o0 = 0, o1 = 1, o2 = 2;
  double l0 = A[0][0], l1 = A[1][1], l2 = A[2][2];
  double tmp; int ti;
  if (l0 < l1){ tmp=l0; l0=l1; l1=tmp; ti=o0; o0=o1; o1=ti; }
  if (l0 < l2){ tmp=l0; l0=l2; l2=tmp; ti=o0; o0=o2; o2=ti; }
  if (l1 < l2){ tmp=l1; l1=l2; l2=tmp; ti=o1; o1=o2; o2=ti; }
  double v0[3] = {V[0][o0], V[1][o0], V[2][o0]};
  double v1[3] = {V[0][o1], V[1][o1], V[2][o1]};
  double v2[3] = {V[0][o2], V[1][o2], V[2][o2]};

  double u0[3], u1[3], u2[3];
  for (int i = 0; i < 3; ++i) u0[i] = H[i*3+0]*v0[0] + H[i*3+1]*v0[1] + H[i*3+2]*v0[2];
  double n0 = sqrt(u0[0]*u0[0] + u0[1]*u0[1] + u0[2]*u0[2]);
  if (n0 > 1e-150){ u0[0]/=n0; u0[1]/=n0; u0[2]/=n0; }
  else { u0[0]=1; u0[1]=0; u0[2]=0; }
  for (int i = 0; i < 3; ++i) u1[i] = H[i*3+0]*v1[0] + H[i*3+1]*v1[1] + H[i*3+2]*v1[2];
  double d01 = u0[0]*u1[0] + u0[1]*u1[1] + u0[2]*u1[2];
  for (int i = 0; i < 3; ++i) u1[i] -= d01*u0[i];
  double n1 = sqrt(u1[0]*u1[0] + u1[1]*u1[1] + u1[2]*u1[2]);
  if (n1 > 1e-150){ u1[0]/=n1; u1[1]/=n1; u1[2]/=n1; }
  else {
    double ax = fabs(u0[0]), ay = fabs(u0[1]), az = fabs(u0[2]);
    double e[3] = {0,0,0};
    if (ax <= ay && ax <= az) e[0] = 1; else if (ay <= az) e[1] = 1; else e[2] = 1;
    double de = u0[0]*e[0] + u0[1]*e[1] + u0[2]*e[2];
    for (int i = 0; i < 3; ++i) u1[i] = e[i] - de*u0[i];
    double nn1 = sqrt(u1[0]*u1[0] + u1[1]*u1[1] + u1[2]*u1[2]);
    for (int i = 0; i < 3; ++i) u1[i] /= nn1;
  }
  u2[0] = u0[1]*u1[2] - u0[2]*u1[1];
  u2[1] = u0[2]*u1[0] - u0[0]*u1[2];
  u2[2] = u0[0]*u1[1] - u0[1]*u1[0];
  double detV = v0[0]*(v1[1]*v2[2] - v1[2]*v2[1])
              - v0[1]*(v1[0]*v2[2] - v1[2]*v2[0])
              + v0[2]*(v1[0]*v2[1] - v1[1]*v2[0]);
  float Rf[9];
  for (int i = 0; i < 3; ++i)
    for (int j = 0; j < 3; ++j)
      Rf[i*3+j] = (float)(v0[i]*u0[j] + v1[i]*u1[j] + detV*(v2[i]*u2[j]));
  float tx = -(Rf[0]*msx + Rf[1]*msy + Rf[2]*msz) + mcx;
  float ty = -(Rf[3]*msx + Rf[4]*msy + Rf[5]*msz) + mcy;
  float tz = -(Rf[6]*msx + Rf[7]*msy + Rf[8]*msz) + mcz;
  float* o = Rt + ((size_t)slot*(NB*NS) + (size_t)id)*12;
  for (int i = 0; i < 9; ++i) o[i] = Rf[i];
  o[9] = tx; o[10] = ty; o[11] = tz;
}

// ---------------- kernel 4: fitness, 16 seeds per block, LDS point slab ----------------
// grid (NS/16, NB, nz), block 256
__global__ __launch_bounds__(256) void ghv_fitness(const float* __restrict__ src,
                                                   const float* __restrict__ tgt,
                                                   const float* __restrict__ Rt,
                                                   int* __restrict__ fit){
  __shared__ float Pf[12288];   // [src x|y|z | tgt x|y|z] each 2048
  int b = blockIdx.y, t = threadIdx.x;
  int slot = blockIdx.z;
  int s0 = blockIdx.x * 16;
  const float4* g4s = (const float4*)(src + (size_t)b*3*NPTS);
  const float4* g4t = (const float4*)(tgt + (size_t)b*3*NPTS);
  float4* l4 = (float4*)Pf;
  for (int i = t; i < 1536; i += 256){
    l4[i] = g4s[i];
    l4[1536 + i] = g4t[i];
  }
  __syncthreads();
  int wv = t >> 6, l = t & 63;
  // wave wv handles seeds s0 + wv*4 .. s0 + wv*4 + 3
  for (int k = 0; k < 4; ++k){
    int s = s0 + wv*4 + k;
    size_t id = (size_t)slot*(NB*NS) + (size_t)((b << 10) + s);
    const float* rt = Rt + id*12;
    float R0 = rt[0], R1 = rt[1], R2 = rt[2];
    float R3 = rt[3], R4 = rt[4], R5 = rt[5];
    float R6 = rt[6], R7 = rt[7], R8 = rt[8];
    float t0 = rt[9], t1 = rt[10], t2 = rt[11];
    int cnt = 0;
    for (int n = l; n < NPTS; n += 64){
      float x = Pf[n], y = Pf[2048 + n], z = Pf[4096 + n];
      float px = R0*x + R1*y + R2*z + t0;
      float py = R3*x + R4*y + R5*z + t1;
      float pz = R6*x + R7*y + R8*z + t2;
      float dx = px - Pf[6144 + n], dy = py - Pf[8192 + n], dz = pz - Pf[10240 + n];
      float l2 = sqrtf(dx*dx + dy*dy + dz*dz);
      cnt += (l2 < 0.1f) ? 1 : 0;
    }
    for (int off = 32; off >= 1; off >>= 1) cnt += __shfl_down(cnt, off);
    if (l == 0) fit[id] = cnt;
  }
}

// ---------------- kernel 5a: batched final select over all iterations ----------------
__global__ __launch_bounds__(512) void ghv_select_b(const float* __restrict__ Rt,
                                                    const int* __restrict__ fit,
                                                    float* __restrict__ out){
  __shared__ int mc[NITER*NB], mi[NITER*NB];
  __shared__ int best_sh;
  int t = threadIdx.x;
  int w = t >> 6, l = t & 63;
  for (int task = w; task < NITER*NB; task += 8){
    int it = task >> 3, b = task & 7;
    int bc = -1, bi = 0;
    const int* fp = fit + (size_t)it*(NB*NS) + (b << 10);
    for (int s = l; s < NS; s += 64){
      int c = fp[s];
      if (c > bc){ bc = c; bi = s; }
    }
    for (int off = 32; off >= 1; off >>= 1){
      int oc = __shfl_down(bc, off);
      int oi = __shfl_down(bi, off);
      if (oc > bc || (oc == bc && oi < bi)){ bc = oc; bi = oi; }
    }
    if (l == 0){ mc[task] = bc; mi[task] = bi; }
  }
  __syncthreads();
  if (t == 0){
    float dist = 1e8f;
    int best = 0;
    for (int it = 0; it < NITER; ++it){
      int sum = 0;
      for (int b = 0; b < NB; ++b) sum += mc[(it << 3) + b];
      float vv = (float)sum / 16384.0f;
      if (vv < dist){ dist = vv; best = it; }
    }
    best_sh = best;
  }
  __syncthreads();
  int bit = best_sh;
  for (int i = t; i < 96; i += 512){
    float v;
    if (i < 72){
      int bb = i / 9, k = i % 9;
      v = Rt[((size_t)bit*(NB*NS) + (size_t)((bb << 10) + mi[(bit << 3) + bb]))*12 + k];
    } else {
      int ii = i - 72; int bb = ii / 3, k = ii % 3;
      v = Rt[((size_t)bit*(NB*NS) + (size_t)((bb << 10) + mi[(bit << 3) + bb]))*12 + 9 + k];
    }
    out[i] = v;
  }
}

// ---------------- kernel 5b: sequential-path select (fallback) ----------------
__global__ __launch_bounds__(512) void ghv_select_s(const float* __restrict__ Rt,
                                                    const int* __restrict__ fit,
                                                    float* __restrict__ dist_ws,
                                                    float* __restrict__ out,
                                                    int first){
  __shared__ int mc[8], mi[8];
  __shared__ int flag;
  int t = threadIdx.x;
  int b = t >> 6, lane = t & 63;
  int bc = -1, bi = 0;
  for (int s = lane; s < NS; s += 64){
    int c = fit[(b << 10) + s];
    if (c > bc){ bc = c; bi = s; }
  }
  for (int off = 32; off >= 1; off >>= 1){
    int oc = __shfl_down(bc, off);
    int oi = __shfl_down(bi, off);
    if (oc > bc || (oc == bc && oi < bi)){ bc = oc; bi = oi; }
  }
  if (lane == 0){ mc[b] = bc; mi[b] = bi; }
  __syncthreads();
  if (t == 0){
    int sum = 0; for (int i = 0; i < 8; ++i) sum += mc[i];
    float vv = (float)sum / 16384.0f;
    float dist = first ? 1e8f : dist_ws[0];
    int better = (vv < dist) ? 1 : 0;
    if (better) dist_ws[0] = vv;
    flag = better;
  }
  __syncthreads();
  if (flag){
    for (int i = t; i < 96; i += 512){
      float v;
      if (i < 72){
        int bb = i / 9, k = i % 9;
        v = Rt[(size_t)((bb << 10) + mi[bb])*12 + k];
      } else {
        int ii = i - 72; int bb = ii / 3, k = ii % 3;
        v = Rt[(size_t)((bb << 10) + mi[bb])*12 + 9 + k];
      }
      out[i] = v;
    }
  }
}

// ---------------- host ----------------
extern "C" void kernel_launch(void* const* d_in, const int* in_sizes, int n_in,
                              void* d_out, int out_size, void* d_ws, size_t ws_size,
                              hipStream_t stream){
  const float* src = (const float*)d_in[0];
  const float* tgt = (const float*)d_in[1];
  const float* win = (const float*)d_in[2];
  float* out = (float*)d_out;
  char* ws = (char*)d_ws;

  const size_t SEEDS_SZ = (size_t)NB*NS*8*4;     // 262144
  const size_t RT_SZ    = (size_t)NB*NS*12*4;    // 393216
  const size_t NN_SZ    = (size_t)NB*NS*32*2;    // 524288
  const size_t FIT_SZ   = (size_t)NB*NS*4;       // 32768
  const size_t W_SZ     = (size_t)NB*NPTS*4;     // 65536

  // batched layout
  size_t off_w    = 0;
  size_t off_logw = off_w + W_SZ;
  size_t off_seed = off_logw + W_SZ;
  size_t off_Rt   = off_seed + NITER*SEEDS_SZ;
  size_t off_nn   = off_Rt + NITER*RT_SZ;
  size_t off_fit  = off_nn + NITER*NN_SZ;
  size_t need_b   = off_fit + NITER*FIT_SZ;

  if (ws_size >= need_b){
    float* w     = (float*)(ws + off_w);
    float* logw  = (float*)(ws + off_logw);
    float* seeds = (float*)(ws + off_seed);
    float* Rt    = (float*)(ws + off_Rt);
    unsigned short* nnb = (unsigned short*)(ws + off_nn);
    int*   fit   = (int*)(ws + off_fit);

    ghv_softmax<<<NB, 256, 0, stream>>>(win, w, logw);
    ghv_seed   <<<dim3(NB, 1, NITER), 1024, 0, stream>>>(src, tgt, w, logw, seeds, 0, 0);
    ghv_nn     <<<dim3(NS, NB, NITER), 512, 0, stream>>>(seeds, nnb, 0, 0);
    ghv_kabsch <<<dim3(NB*NS/64, 1, NITER), 64, 0, stream>>>(seeds, nnb, Rt, 0, 0);
    ghv_fitness<<<dim3(NS/16, NB, NITER), 256, 0, stream>>>(src, tgt, Rt, fit);
    ghv_select_b<<<1, 512, 0, stream>>>(Rt, fit, out);
  } else {
    // sequential fallback (single slot)
    size_t o_w = 0, o_lw = W_SZ, o_sd = 2*W_SZ, o_rt = o_sd + SEEDS_SZ,
           o_nn2 = o_rt + RT_SZ, o_ft = o_nn2 + NN_SZ, o_ds = o_ft + FIT_SZ;
    float* w     = (float*)(ws + o_w);
    float* logw  = (float*)(ws + o_lw);
    float* seeds = (float*)(ws + o_sd);
    float* Rt    = (float*)(ws + o_rt);
    unsigned short* nnb = (unsigned short*)(ws + o_nn2);
    int*   fit   = (int*)(ws + o_ft);
    float* dist  = (float*)(ws + o_ds);

    ghv_softmax<<<NB, 256, 0, stream>>>(win, w, logw);
    for (int it = 0; it < NITER; ++it){
      ghv_seed   <<<dim3(NB, 1, 1), 1024, 0, stream>>>(src, tgt, w, logw, seeds, it, 1);
      ghv_nn     <<<dim3(NS, NB, 1), 512, 0, stream>>>(seeds, nnb, it, 1);
      ghv_kabsch <<<dim3(NB*NS/64, 1, 1), 64, 0, stream>>>(seeds, nnb, Rt, it, 1);
      ghv_fitness<<<dim3(NS/16, NB, 1), 256, 0, stream>>>(src, tgt, Rt, fit);
      ghv_select_s<<<1, 512, 0, stream>>>(Rt, fit, dist, out, (it == 0) ? 1 : 0);
    }
  }
}

// Round 4
// 933.017 us; speedup vs baseline: 3.7459x; 1.2830x over previous
//
#include <hip/hip_runtime.h>
#include <stdint.h>
#include <math.h>

// Match XLA-CPU's unfused mul/add on threshold-critical math.
#pragma clang fp contract(off)

#define NB    8
#define NPTS  2048
#define NS    1024
#define NG    30
#define NITER 10

typedef unsigned long long ull;

// ---------------- threefry2x32 (Random123 / JAX, 20 rounds) ----------------
__host__ __device__ __forceinline__ uint32_t rotl32(uint32_t x, int r){
  return (x << r) | (x >> (32 - r));
}
__host__ __device__ __forceinline__ void tf2x32(uint32_t k0, uint32_t k1,
                                                uint32_t x0, uint32_t x1,
                                                uint32_t& o0, uint32_t& o1){
  uint32_t k2 = k0 ^ k1 ^ 0x1BD11BDAu;
  x0 += k0; x1 += k1;
#define TFR(r) { x0 += x1; x1 = rotl32(x1, (r)); x1 ^= x0; }
  TFR(13) TFR(15) TFR(26) TFR(6)
  x0 += k1; x1 += k2 + 1u;
  TFR(17) TFR(29) TFR(16) TFR(24)
  x0 += k2; x1 += k0 + 2u;
  TFR(13) TFR(15) TFR(26) TFR(6)
  x0 += k0; x1 += k1 + 3u;
  TFR(17) TFR(29) TFR(16) TFR(24)
  x0 += k1; x1 += k2 + 4u;
  TFR(13) TFR(15) TFR(26) TFR(6)
  x0 += k2; x1 += k0 + 5u;
#undef TFR
  o0 = x0; o1 = x1;
}

// partitionable threefry: bits[e] = o0^o1 of tf(key,(0,e))
__device__ __forceinline__ uint32_t rand_bits(uint32_t k0, uint32_t k1, uint32_t e){
  uint32_t o0, o1; tf2x32(k0, k1, 0u, e, o0, o1);
  return o0 ^ o1;
}

// split(fold_in(key(42), it)): k_i = tf(folded, (0, i)), i in {0,1}
__device__ __forceinline__ void derive_key(int it, uint32_t which,
                                           uint32_t& a, uint32_t& b){
  uint32_t fa, fb;
  tf2x32(0u, 42u, 0u, (uint32_t)it, fa, fb);
  tf2x32(fa, fb, 0u, which, a, b);
}

// jax.random.uniform(minval=1e-9, maxval=1.0) -> gumbel
__device__ __forceinline__ float gumbel_from(uint32_t bits){
  float f = __uint_as_float((bits >> 9) | 0x3f800000u) - 1.0f;  // [0,1)
  float u = fmaxf(1e-9f, f + 1e-9f);
  return -logf(-logf(u));
}

// ---------------- sort keys: (value desc, index asc) ----------------
__device__ __forceinline__ ull packkey(float v, uint32_t idx){
  uint32_t u = __float_as_uint(v);
  u = (u & 0x80000000u) ? ~u : (u | 0x80000000u);
  return ((ull)u << 32) | (ull)(0xFFFFFFFFu - idx);
}
__device__ __forceinline__ uint32_t unpackidx(ull k){
  return 0xFFFFFFFFu - (uint32_t)(k & 0xFFFFFFFFull);
}

__device__ __forceinline__ void bitonic_desc(ull* a, int M, int t, int T){
  for (int k = 2; k <= M; k <<= 1){
    for (int j = k >> 1; j > 0; j >>= 1){
      for (int i = t; i < M; i += T){
        int ixj = i ^ j;
        if (ixj > i){
          ull ai = a[i], aj = a[ixj];
          bool desc = ((i & k) == 0);
          if (desc ? (ai < aj) : (ai > aj)){ a[i] = aj; a[ixj] = ai; }
        }
      }
      __syncthreads();
    }
  }
}

// -------- wave-level (64-lane) register bitonic helpers, u64 keys --------
__device__ __forceinline__ ull shfl_xor_u64(ull x, int mask){
  return (ull)__shfl_xor((long long)x, mask, 64);
}

__device__ __forceinline__ ull sort32_desc(ull key, int l){
  int i = l & 31;
#pragma unroll
  for (int k = 2; k <= 16; k <<= 1){
#pragma unroll
    for (int j = k >> 1; j > 0; j >>= 1){
      ull other = shfl_xor_u64(key, j);
      bool up = ((l & j) == 0);
      bool take_max = (((i & k) == 0) == up);
      bool omax = other > key;
      key = (take_max == omax) ? other : key;
    }
  }
#pragma unroll
  for (int j = 16; j > 0; j >>= 1){
    ull other = shfl_xor_u64(key, j);
    bool up = ((l & j) == 0);
    bool omax = other > key;
    key = (up == omax) ? other : key;
  }
  return key;
}

__device__ __forceinline__ ull merge64_desc(ull key, int l){
#pragma unroll
  for (int j = 32; j > 0; j >>= 1){
    ull other = shfl_xor_u64(key, j);
    bool up = ((l & j) == 0);
    bool omax = other > key;
    key = (up == omax) ? other : key;
  }
  return key;
}

__device__ __forceinline__ ull mergehalves_desc(ull key, int l){
  ull rev = shfl_xor_u64(key, 31);
  if (l >= 32) key = rev;
  return merge64_desc(key, l);
}

// ---------------- kernel 0: nan/inf cleanup + softmax + log ----------------
__global__ __launch_bounds__(256) void ghv_softmax(const float* __restrict__ win,
                                                   float* __restrict__ w,
                                                   float* __restrict__ logw){
  int b = blockIdx.x, t = threadIdx.x;
  __shared__ float sh[NPTS];
  __shared__ float red[4];
  __shared__ float bcast;
  for (int n = t; n < NPTS; n += 256){
    float x = win[b*NPTS + n];
    if (isnan(x)) x = 1e-7f;
    if (isinf(x)) x = 1.0f;
    sh[n] = x;
  }
  __syncthreads();
  float m = -INFINITY;
  for (int n = t; n < NPTS; n += 256) m = fmaxf(m, sh[n]);
  for (int off = 32; off >= 1; off >>= 1) m = fmaxf(m, __shfl_down(m, off));
  if ((t & 63) == 0) red[t >> 6] = m;
  __syncthreads();
  if (t == 0) bcast = fmaxf(fmaxf(red[0], red[1]), fmaxf(red[2], red[3]));
  __syncthreads();
  float mx = bcast;
  float ss = 0.0f;
  for (int n = t; n < NPTS; n += 256){ float e = expf(sh[n] - mx); sh[n] = e; ss += e; }
  for (int off = 32; off >= 1; off >>= 1) ss += __shfl_down(ss, off);
  if ((t & 63) == 0) red[t >> 6] = ss;
  __syncthreads();
  if (t == 0) bcast = red[0] + red[1] + red[2] + red[3];
  __syncthreads();
  float tot = bcast;
  for (int n = t; n < NPTS; n += 256){
    float wv = sh[n] / tot;
    w[b*NPTS + n] = wv;
    logw[b*NPTS + n] = logf(wv);
  }
}

// ---------------- kernel 1: seed gumbel top-1024 + gather ----------------
__global__ __launch_bounds__(1024) void ghv_seed(const float* __restrict__ src,
                                                 const float* __restrict__ tgt,
                                                 const float* __restrict__ w,
                                                 const float* __restrict__ logw,
                                                 float* __restrict__ seeds,
                                                 int it0, int seq){
  __shared__ ull keys[NPTS];
  __shared__ uint32_t kk[2];
  int b = blockIdx.x, t = threadIdx.x;
  int it = it0 + blockIdx.z;
  int slot = seq ? 0 : it;
  if (t == 0){ derive_key(it, 0u, kk[0], kk[1]); }
  __syncthreads();
  uint32_t k0 = kk[0], k1 = kk[1];
  for (int n = t; n < NPTS; n += 1024){
    uint32_t bits = rand_bits(k0, k1, (uint32_t)(b*NPTS + n));
    float v = logw[b*NPTS + n] + gumbel_from(bits);
    keys[n] = packkey(v, (uint32_t)n);
  }
  __syncthreads();
  bitonic_desc(keys, NPTS, t, 1024);
  int s = t;
  uint32_t idx = unpackidx(keys[s]);
  const float* sb = src + b*3*NPTS;
  const float* tb = tgt + b*3*NPTS;
  float* sp = seeds + (size_t)slot*(NB*NS*8) + (size_t)((b << 10) + s) * 8;
  sp[0] = sb[idx]; sp[1] = sb[NPTS + idx]; sp[2] = sb[2*NPTS + idx];
  sp[3] = tb[idx]; sp[4] = tb[NPTS + idx]; sp[5] = tb[2*NPTS + idx];
  sp[6] = w[b*NPTS + idx]; sp[7] = 0.0f;
}

// ---------------- kernel 2: consensus + gumbel top-30 per (b,s) row ----------------
// Exact threshold prune (T = min over 32 chunk-maxes) -> compact -> small sort.
// grid (NS, NB, nz), block 512
__global__ __launch_bounds__(512) void ghv_nn(const float* __restrict__ seeds,
                                              unsigned short* __restrict__ nnb,
                                              int it0, int seq){
  __shared__ float red[8];
  __shared__ float srow[8];
  __shared__ float rowsum_sh;
  __shared__ float cmax[32];
  __shared__ float Tsh;
  __shared__ int cnt_sh;
  __shared__ uint32_t kk[2];
  __shared__ ull kbuf[NS];    // survivors (fast) / all keys (fallback)
  __shared__ ull sbuf[256];
  __shared__ ull sbuf2[128];

  int s = blockIdx.x, b = blockIdx.y, t = threadIdx.x;
  int it = it0 + blockIdx.z;
  int slot = seq ? 0 : it;
  const float* sdat = seeds + (size_t)slot*(NB*NS*8);
  size_t outoff = ((size_t)slot*(NB*NS) + (size_t)((b << 10) + s))*32;
  int wv = t >> 6, l = t & 63;

  if (t < 8) srow[t] = sdat[(size_t)((b << 10) + s)*8 + t];
  if (t == 0){ derive_key(it, 1u, kk[0], kk[1]); cnt_sh = 0; }
  __syncthreads();
  uint32_t k0 = kk[0], k1 = kk[1];

  // consensus for this thread's two elements j = t, t+512 (kept in regs)
  float consr[2];
  float part = 0.0f;
#pragma unroll
  for (int q = 0; q < 2; ++q){
    int j = t + q*512;
    const float4* jp = (const float4*)(sdat + (size_t)((b << 10) + j)*8);
    float4 p0 = jp[0], p1 = jp[1];
    float dxs = srow[0]-p0.x, dys = srow[1]-p0.y, dzs = srow[2]-p0.z;
    float ds  = sqrtf(dxs*dxs + dys*dys + dzs*dzs);
    float dxc = srow[3]-p0.w, dyc = srow[4]-p1.x, dzc = srow[5]-p1.y;
    float dc  = sqrtf(dxc*dxc + dyc*dyc + dzc*dzc);
    float diff = ds - dc;
    float cons = expf((-(diff*diff)) / 0.01f);
    cons = fmaxf(cons, 0.1f);
    consr[q] = cons;
    part += cons;
  }
  for (int off = 32; off >= 1; off >>= 1) part += __shfl_down(part, off);
  if ((t & 63) == 0) red[t >> 6] = part;
  __syncthreads();
  if (t == 0){ float tot = 0.0f; for (int i = 0; i < 8; ++i) tot += red[i]; rowsum_sh = tot; }
  __syncthreads();
  float rowsum = rowsum_sh;

  // keys for e = t, t+512 (byte-identical value math to previous rounds)
  float v0, v1; ull key0, key1;
  {
    int e = t;
    uint32_t bits = rand_bits(k0, k1, (uint32_t)((b << 20) + (s << 10) + e));
    v0 = logf(consr[0] / rowsum) + gumbel_from(bits);
    key0 = packkey(v0, (uint32_t)e);
  }
  {
    int e = t + 512;
    uint32_t bits = rand_bits(k0, k1, (uint32_t)((b << 20) + (s << 10) + e));
    v1 = logf(consr[1] / rowsum) + gumbel_from(bits);
    key1 = packkey(v1, (uint32_t)e);
  }

  // chunk maxes: chunk = 32 consecutive elements = one half-wave
  {
    float cm0 = v0;
#pragma unroll
    for (int j = 1; j <= 16; j <<= 1) cm0 = fmaxf(cm0, __shfl_xor(cm0, j));
    if ((l & 31) == 0) cmax[(wv << 1) + (l >> 5)] = cm0;
    float cm1 = v1;
#pragma unroll
    for (int j = 1; j <= 16; j <<= 1) cm1 = fmaxf(cm1, __shfl_xor(cm1, j));
    if ((l & 31) == 0) cmax[16 + (wv << 1) + (l >> 5)] = cm1;
  }
  __syncthreads();
  if (t < 32){
    float m = cmax[t];
#pragma unroll
    for (int j = 1; j <= 16; j <<= 1) m = fminf(m, __shfl_xor(m, j));
    if (t == 0) Tsh = m;
  }
  __syncthreads();
  float T = Tsh;

  // compact survivors (v >= T). >=32 guaranteed; order fixed by final sort.
  bool kp0 = (v0 >= T), kp1 = (v1 >= T);
  ull b0m = __ballot(kp0), b1m = __ballot(kp1);
  int c0 = __popcll(b0m);
  int base = 0;
  if (l == 0) base = atomicAdd(&cnt_sh, c0 + __popcll(b1m));
  base = __shfl(base, 0);
  ull ltm = (l == 0) ? 0ull : ((1ull << l) - 1ull);
  if (kp0) kbuf[base + __popcll(b0m & ltm)] = key0;
  if (kp1) kbuf[base + c0 + __popcll(b1m & ltm)] = key1;
  __syncthreads();
  int n = cnt_sh;

  if (n <= 512){
    if (t >= n) kbuf[t] = 0ull;   // pad [n,512) with -inf sentinel
    __syncthreads();
    ull key = 0ull;
    if (wv * 64 < n){
      key = kbuf[t];
      key = sort32_desc(key, l);
      key = mergehalves_desc(key, l);   // wave's 64 sorted desc
    }
    if (l < 32) sbuf[(wv << 5) + l] = key;
    __syncthreads();
    if (wv < 4){
      ull k2 = 0ull;
      if (wv * 128 < n){
        k2 = (l < 32) ? sbuf[(wv << 6) + l] : sbuf[(wv << 6) + 95 - l];
        k2 = merge64_desc(k2, l);
      }
      if (l < 32) sbuf2[(wv << 5) + l] = k2;
    }
    __syncthreads();
    if (wv < 2){
      ull k2 = (l < 32) ? sbuf2[(wv << 6) + l] : sbuf2[(wv << 6) + 95 - l];
      k2 = merge64_desc(k2, l);
      if (l < 32) sbuf[(wv << 5) + l] = k2;
    }
    __syncthreads();
    if (wv == 0){
      ull k2 = (l < 32) ? sbuf[l] : sbuf[95 - l];
      k2 = merge64_desc(k2, l);
      if (l < 32){
        unsigned short vidx = (l < NG) ? (unsigned short)unpackidx(k2) : 0;
        nnb[outoff + l] = vidx;
      }
    }
  } else {
    // fallback: full LDS bitonic over all 1024 keys (proven R1 path)
    kbuf[t] = key0;
    kbuf[t + 512] = key1;
    __syncthreads();
    bitonic_desc(kbuf, NS, t, 512);
    if (t < 32){
      unsigned short vidx = (t < NG) ? (unsigned short)unpackidx(kbuf[t]) : 0;
      nnb[outoff + t] = vidx;
    }
  }
}

// ---------------- kernel 3: weighted Kabsch + 3x3 SVD (double) ----------------
// grid (NB*NS/64, 1, nz), block 64
__global__ __launch_bounds__(64) void ghv_kabsch(const float* __restrict__ seeds,
                                                 const unsigned short* __restrict__ nnb,
                                                 float* __restrict__ Rt,
                                                 int it0, int seq){
  int id = blockIdx.x*64 + threadIdx.x;
  int it = it0 + blockIdx.z;
  int slot = seq ? 0 : it;
  int b = id >> 10;
  const float* sdat = seeds + (size_t)slot*(NB*NS*8);
  const unsigned short* nnp = nnb + ((size_t)slot*(NB*NS) + (size_t)id)*32;

  float sxs=0, sys=0, szs=0, cxs=0, cys=0, czs=0, wsum=0;
  for (int g = 0; g < NG; ++g){
    int j = nnp[g];
    const float4* jp = (const float4*)(sdat + (size_t)((b << 10) + j)*8);
    float4 p0 = jp[0], p1 = jp[1];
    sxs += p0.x; sys += p0.y; szs += p0.z;
    cxs += p0.w; cys += p1.x; czs += p1.y;
    wsum += p1.z;
  }
  float msx = sxs/30.0f, msy = sys/30.0f, msz = szs/30.0f;
  float mcx = cxs/30.0f, mcy = cys/30.0f, mcz = czs/30.0f;

  float Hf[9] = {0,0,0,0,0,0,0,0,0};
  for (int g = 0; g < NG; ++g){
    int j = nnp[g];
    const float4* jp = (const float4*)(sdat + (size_t)((b << 10) + j)*8);
    float4 p0 = jp[0], p1 = jp[1];
    float wg = p1.z / wsum;
    float a0 = p0.x - msx, a1 = p0.y - msy, a2 = p0.z - msz;
    float b0 = p0.w - mcx, b1 = p1.x - mcy, b2 = p1.y - mcz;
    float a0w = a0*wg, a1w = a1*wg, a2w = a2*wg;
    Hf[0] += a0w*b0; Hf[1] += a0w*b1; Hf[2] += a0w*b2;
    Hf[3] += a1w*b0; Hf[4] += a1w*b1; Hf[5] += a1w*b2;
    Hf[6] += a2w*b0; Hf[7] += a2w*b1; Hf[8] += a2w*b2;
  }

  double H[9]; for (int i = 0; i < 9; ++i) H[i] = (double)Hf[i];
  double A[3][3];
  A[0][0] = H[0]*H[0] + H[3]*H[3] + H[6]*H[6];
  A[0][1] = H[0]*H[1] + H[3]*H[4] + H[6]*H[7];
  A[0][2] = H[0]*H[2] + H[3]*H[5] + H[6]*H[8];
  A[1][1] = H[1]*H[1] + H[4]*H[4] + H[7]*H[7];
  A[1][2] = H[1]*H[2] + H[4]*H[5] + H[7]*H[8];
  A[2][2] = H[2]*H[2] + H[5]*H[5] + H[8]*H[8];
  A[1][0] = A[0][1]; A[2][0] = A[0][2]; A[2][1] = A[1][2];
  double V[3][3] = {{1,0,0},{0,1,0},{0,0,1}};
  for (int sw = 0; sw < 12; ++sw){
    for (int p = 0; p < 2; ++p){
      for (int q = p+1; q < 3; ++q){
        double apq = A[p][q];
        if (fabs(apq) > 1e-300){
          double th = (A[q][q] - A[p][p]) / (2.0*apq);
          double tt = copysign(1.0, th) / (fabs(th) + sqrt(1.0 + th*th));
          double c  = 1.0 / sqrt(1.0 + tt*tt), sn = tt*c;
          int r = 3 - p - q;
          double app = A[p][p], aqq = A[q][q];
          double arp = A[r][p], arq = A[r][q];
          A[p][p] = app - tt*apq;
          A[q][q] = aqq + tt*apq;
          A[p][q] = 0.0; A[q][p] = 0.0;
          A[r][p] = c*arp - sn*arq; A[p][r] = A[r][p];
          A[r][q] = sn*arp + c*arq; A[q][r] = A[r][q];
          for (int kk = 0; kk < 3; ++kk){
            double vp = V[kk][p], vq = V[kk][q];
            V[kk][p] = c*vp - sn*vq;
            V[kk][q] = sn*vp + c*vq;
          }
        }
      }
    }
  }
  int o0 = 0, o1 = 1, o2 = 2;
  double l0 = A[0][0], l1 = A[1][1], l2 = A[2][2];
  double tmp; int ti;
  if (l0 < l1){ tmp=l0; l0=l1; l1=tmp; ti=o0; o0=o1; o1=ti; }
  if (l0 < l2){ tmp=l0; l0=l2; l2=tmp; ti=o0; o0=o2; o2=ti; }
  if (l1 < l2){ tmp=l1; l1=l2; l2=tmp; ti=o1; o1=o2; o2=ti; }
  double v0[3] = {V[0][o0], V[1][o0], V[2][o0]};
  double v1[3] = {V[0][o1], V[1][o1], V[2][o1]};
  double v2[3] = {V[0][o2], V[1][o2], V[2][o2]};

  double u0[3], u1[3], u2[3];
  for (int i = 0; i < 3; ++i) u0[i] = H[i*3+0]*v0[0] + H[i*3+1]*v0[1] + H[i*3+2]*v0[2];
  double n0 = sqrt(u0[0]*u0[0] + u0[1]*u0[1] + u0[2]*u0[2]);
  if (n0 > 1e-150){ u0[0]/=n0; u0[1]/=n0; u0[2]/=n0; }
  else { u0[0]=1; u0[1]=0; u0[2]=0; }
  for (int i = 0; i < 3; ++i) u1[i] = H[i*3+0]*v1[0] + H[i*3+1]*v1[1] + H[i*3+2]*v1[2];
  double d01 = u0[0]*u1[0] + u0[1]*u1[1] + u0[2]*u1[2];
  for (int i = 0; i < 3; ++i) u1[i] -= d01*u0[i];
  double n1 = sqrt(u1[0]*u1[0] + u1[1]*u1[1] + u1[2]*u1[2]);
  if (n1 > 1e-150){ u1[0]/=n1; u1[1]/=n1; u1[2]/=n1; }
  else {
    double ax = fabs(u0[0]), ay = fabs(u0[1]), az = fabs(u0[2]);
    double e[3] = {0,0,0};
    if (ax <= ay && ax <= az) e[0] = 1; else if (ay <= az) e[1] = 1; else e[2] = 1;
    double de = u0[0]*e[0] + u0[1]*e[1] + u0[2]*e[2];
    for (int i = 0; i < 3; ++i) u1[i] = e[i] - de*u0[i];
    double nn1 = sqrt(u1[0]*u1[0] + u1[1]*u1[1] + u1[2]*u1[2]);
    for (int i = 0; i < 3; ++i) u1[i] /= nn1;
  }
  u2[0] = u0[1]*u1[2] - u0[2]*u1[1];
  u2[1] = u0[2]*u1[0] - u0[0]*u1[2];
  u2[2] = u0[0]*u1[1] - u0[1]*u1[0];
  double detV = v0[0]*(v1[1]*v2[2] - v1[2]*v2[1])
              - v0[1]*(v1[0]*v2[2] - v1[2]*v2[0])
              + v0[2]*(v1[0]*v2[1] - v1[1]*v2[0]);
  float Rf[9];
  for (int i = 0; i < 3; ++i)
    for (int j = 0; j < 3; ++j)
      Rf[i*3+j] = (float)(v0[i]*u0[j] + v1[i]*u1[j] + detV*(v2[i]*u2[j]));
  float tx = -(Rf[0]*msx + Rf[1]*msy + Rf[2]*msz) + mcx;
  float ty = -(Rf[3]*msx + Rf[4]*msy + Rf[5]*msz) + mcy;
  float tz = -(Rf[6]*msx + Rf[7]*msy + Rf[8]*msz) + mcz;
  float* o = Rt + ((size_t)slot*(NB*NS) + (size_t)id)*12;
  for (int i = 0; i < 9; ++i) o[i] = Rf[i];
  o[9] = tx; o[10] = ty; o[11] = tz;
}

// ---------------- kernel 4: fitness, 16 seeds per block, LDS point slab ----------------
// grid (NS/16, NB, nz), block 256
__global__ __launch_bounds__(256) void ghv_fitness(const float* __restrict__ src,
                                                   const float* __restrict__ tgt,
                                                   const float* __restrict__ Rt,
                                                   int* __restrict__ fit){
  __shared__ float Pf[12288];   // [src x|y|z | tgt x|y|z] each 2048
  int b = blockIdx.y, t = threadIdx.x;
  int slot = blockIdx.z;
  int s0 = blockIdx.x * 16;
  const float4* g4s = (const float4*)(src + (size_t)b*3*NPTS);
  const float4* g4t = (const float4*)(tgt + (size_t)b*3*NPTS);
  float4* l4 = (float4*)Pf;
  for (int i = t; i < 1536; i += 256){
    l4[i] = g4s[i];
    l4[1536 + i] = g4t[i];
  }
  __syncthreads();
  int wv = t >> 6, l = t & 63;
  for (int k = 0; k < 4; ++k){
    int s = s0 + wv*4 + k;
    size_t id = (size_t)slot*(NB*NS) + (size_t)((b << 10) + s);
    const float* rt = Rt + id*12;
    float R0 = rt[0], R1 = rt[1], R2 = rt[2];
    float R3 = rt[3], R4 = rt[4], R5 = rt[5];
    float R6 = rt[6], R7 = rt[7], R8 = rt[8];
    float t0 = rt[9], t1 = rt[10], t2 = rt[11];
    int cnt = 0;
    for (int n = l; n < NPTS; n += 64){
      float x = Pf[n], y = Pf[2048 + n], z = Pf[4096 + n];
      float px = R0*x + R1*y + R2*z + t0;
      float py = R3*x + R4*y + R5*z + t1;
      float pz = R6*x + R7*y + R8*z + t2;
      float dx = px - Pf[6144 + n], dy = py - Pf[8192 + n], dz = pz - Pf[10240 + n];
      float l2 = sqrtf(dx*dx + dy*dy + dz*dz);
      cnt += (l2 < 0.1f) ? 1 : 0;
    }
    for (int off = 32; off >= 1; off >>= 1) cnt += __shfl_down(cnt, off);
    if (l == 0) fit[id] = cnt;
  }
}

// ---------------- kernel 5a: batched final select over all iterations ----------------
__global__ __launch_bounds__(512) void ghv_select_b(const float* __restrict__ Rt,
                                                    const int* __restrict__ fit,
                                                    float* __restrict__ out){
  __shared__ int mc[NITER*NB], mi[NITER*NB];
  __shared__ int best_sh;
  int t = threadIdx.x;
  int w = t >> 6, l = t & 63;
  for (int task = w; task < NITER*NB; task += 8){
    int it = task >> 3, b = task & 7;
    int bc = -1, bi = 0;
    const int* fp = fit + (size_t)it*(NB*NS) + (b << 10);
    for (int s = l; s < NS; s += 64){
      int c = fp[s];
      if (c > bc){ bc = c; bi = s; }
    }
    for (int off = 32; off >= 1; off >>= 1){
      int oc = __shfl_down(bc, off);
      int oi = __shfl_down(bi, off);
      if (oc > bc || (oc == bc && oi < bi)){ bc = oc; bi = oi; }
    }
    if (l == 0){ mc[task] = bc; mi[task] = bi; }
  }
  __syncthreads();
  if (t == 0){
    float dist = 1e8f;
    int best = 0;
    for (int it = 0; it < NITER; ++it){
      int sum = 0;
      for (int b = 0; b < NB; ++b) sum += mc[(it << 3) + b];
      float vv = (float)sum / 16384.0f;
      if (vv < dist){ dist = vv; best = it; }
    }
    best_sh = best;
  }
  __syncthreads();
  int bit = best_sh;
  for (int i = t; i < 96; i += 512){
    float v;
    if (i < 72){
      int bb = i / 9, k = i % 9;
      v = Rt[((size_t)bit*(NB*NS) + (size_t)((bb << 10) + mi[(bit << 3) + bb]))*12 + k];
    } else {
      int ii = i - 72; int bb = ii / 3, k = ii % 3;
      v = Rt[((size_t)bit*(NB*NS) + (size_t)((bb << 10) + mi[(bit << 3) + bb]))*12 + 9 + k];
    }
    out[i] = v;
  }
}

// ---------------- kernel 5b: sequential-path select (fallback) ----------------
__global__ __launch_bounds__(512) void ghv_select_s(const float* __restrict__ Rt,
                                                    const int* __restrict__ fit,
                                                    float* __restrict__ dist_ws,
                                                    float* __restrict__ out,
                                                    int first){
  __shared__ int mc[8], mi[8];
  __shared__ int flag;
  int t = threadIdx.x;
  int b = t >> 6, lane = t & 63;
  int bc = -1, bi = 0;
  for (int s = lane; s < NS; s += 64){
    int c = fit[(b << 10) + s];
    if (c > bc){ bc = c; bi = s; }
  }
  for (int off = 32; off >= 1; off >>= 1){
    int oc = __shfl_down(bc, off);
    int oi = __shfl_down(bi, off);
    if (oc > bc || (oc == bc && oi < bi)){ bc = oc; bi = oi; }
  }
  if (lane == 0){ mc[b] = bc; mi[b] = bi; }
  __syncthreads();
  if (t == 0){
    int sum = 0; for (int i = 0; i < 8; ++i) sum += mc[i];
    float vv = (float)sum / 16384.0f;
    float dist = first ? 1e8f : dist_ws[0];
    int better = (vv < dist) ? 1 : 0;
    if (better) dist_ws[0] = vv;
    flag = better;
  }
  __syncthreads();
  if (flag){
    for (int i = t; i < 96; i += 512){
      float v;
      if (i < 72){
        int bb = i / 9, k = i % 9;
        v = Rt[(size_t)((bb << 10) + mi[bb])*12 + k];
      } else {
        int ii = i - 72; int bb = ii / 3, k = ii % 3;
        v = Rt[(size_t)((bb << 10) + mi[bb])*12 + 9 + k];
      }
      out[i] = v;
    }
  }
}

// ---------------- host ----------------
extern "C" void kernel_launch(void* const* d_in, const int* in_sizes, int n_in,
                              void* d_out, int out_size, void* d_ws, size_t ws_size,
                              hipStream_t stream){
  const float* src = (const float*)d_in[0];
  const float* tgt = (const float*)d_in[1];
  const float* win = (const float*)d_in[2];
  float* out = (float*)d_out;
  char* ws = (char*)d_ws;

  const size_t SEEDS_SZ = (size_t)NB*NS*8*4;     // 262144
  const size_t RT_SZ    = (size_t)NB*NS*12*4;    // 393216
  const size_t NN_SZ    = (size_t)NB*NS*32*2;    // 524288
  const size_t FIT_SZ   = (size_t)NB*NS*4;       // 32768
  const size_t W_SZ     = (size_t)NB*NPTS*4;     // 65536

  size_t off_w    = 0;
  size_t off_logw = off_w + W_SZ;
  size_t off_seed = off_logw + W_SZ;
  size_t off_Rt   = off_seed + NITER*SEEDS_SZ;
  size_t off_nn   = off_Rt + NITER*RT_SZ;
  size_t off_fit  = off_nn + NITER*NN_SZ;
  size_t need_b   = off_fit + NITER*FIT_SZ;

  if (ws_size >= need_b){
    float* w     = (float*)(ws + off_w);
    float* logw  = (float*)(ws + off_logw);
    float* seeds = (float*)(ws + off_seed);
    float* Rt    = (float*)(ws + off_Rt);
    unsigned short* nnb = (unsigned short*)(ws + off_nn);
    int*   fit   = (int*)(ws + off_fit);

    ghv_softmax<<<NB, 256, 0, stream>>>(win, w, logw);
    ghv_seed   <<<dim3(NB, 1, NITER), 1024, 0, stream>>>(src, tgt, w, logw, seeds, 0, 0);
    ghv_nn     <<<dim3(NS, NB, NITER), 512, 0, stream>>>(seeds, nnb, 0, 0);
    ghv_kabsch <<<dim3(NB*NS/64, 1, NITER), 64, 0, stream>>>(seeds, nnb, Rt, 0, 0);
    ghv_fitness<<<dim3(NS/16, NB, NITER), 256, 0, stream>>>(src, tgt, Rt, fit);
    ghv_select_b<<<1, 512, 0, stream>>>(Rt, fit, out);
  } else {
    size_t o_w = 0, o_lw = W_SZ, o_sd = 2*W_SZ, o_rt = o_sd + SEEDS_SZ,
           o_nn2 = o_rt + RT_SZ, o_ft = o_nn2 + NN_SZ, o_ds = o_ft + FIT_SZ;
    float* w     = (float*)(ws + o_w);
    float* logw  = (float*)(ws + o_lw);
    float* seeds = (float*)(ws + o_sd);
    float* Rt    = (float*)(ws + o_rt);
    unsigned short* nnb = (unsigned short*)(ws + o_nn2);
    int*   fit   = (int*)(ws + o_ft);
    float* dist  = (float*)(ws + o_ds);

    ghv_softmax<<<NB, 256, 0, stream>>>(win, w, logw);
    for (int it = 0; it < NITER; ++it){
      ghv_seed   <<<dim3(NB, 1, 1), 1024, 0, stream>>>(src, tgt, w, logw, seeds, it, 1);
      ghv_nn     <<<dim3(NS, NB, 1), 512, 0, stream>>>(seeds, nnb, it, 1);
      ghv_kabsch <<<dim3(NB*NS/64, 1, 1), 64, 0, stream>>>(seeds, nnb, Rt, it, 1);
      ghv_fitness<<<dim3(NS/16, NB, 1), 256, 0, stream>>>(src, tgt, Rt, fit);
      ghv_select_s<<<1, 512, 0, stream>>>(Rt, fit, dist, out, (it == 0) ? 1 : 0);
    }
  }
}